// Round 2
// baseline (1025.558 us; speedup 1.0000x reference)
//
#include <hip/hip_runtime.h>

// ---------------- problem dims ----------------
#define T_DIM 256
#define B_DIM 512
#define D_DIM 128
#define H_DIM 128
#define A_DIM 8
#define N_ROWS (T_DIM*B_DIM)   // 131072 flattened rows
#define NT (N_ROWS/16)         // 8192 row tiles of 16
#define NCHUNK 8               // time chunks per row for segment-parallel GRU

typedef __attribute__((ext_vector_type(4))) float f32x4;
typedef __attribute__((ext_vector_type(8))) short bf16x8;  // 8 bf16 in 4 VGPRs
typedef __attribute__((ext_vector_type(4))) short bf16x4;

// ---------------- workspace layout (bytes) ----------------
#define OFF_PSUM   0ull                    // 1024 blocks * 128 * f64 = 1 MB
#define OFF_PSQ    1048576ull              // 1 MB
#define OFF_STATM  2097152ull              // 128 f32
#define OFF_STATI  2097664ull              // 128 f32
#define OFF_WEMB   2098176ull              // 32768 B
#define OFF_WI     2130944ull              // 98304 B
#define OFF_WHHI   2229248ull              // 98304 B
#define OFF_WHLO   2327552ull              // 98304 B
#define OFF_WACT   2425856ull              // 32768 B
#define OFF_WHEAD  2458624ull              // 4096 B
#define OFF_T0     2462720ull              // 8*512 int = 16384 B
#define OFF_LEN    2479104ull              // 16384 B
#define OFF_XG     4194304ull              // NT*24*64*4 bf16 = 96 MB (C/D-frag order)
#define OFF_YS     104857600ull            // NT*8*64*4 bf16 = 32 MB (C/D-frag order)
// total ws need: ~132 MB

// ---------------- output layout (f32 elements) ----------------
#define OUT_H      0          // h_last [512,128]
#define OUT_ALPHA  65536      // [256,512,8]
#define OUT_BETA   1114112    // [256,512,8]
#define OUT_M      2162688    // [128]
#define OUT_S      2162816    // [128]

__device__ inline short f2bf(float x){              // round-to-nearest-even f32->bf16
  union { float f; unsigned u; } v; v.f = x;
  unsigned r = v.u + 0x7FFFu + ((v.u>>16)&1u);
  return (short)(r>>16);
}
__device__ inline float bf2f(short h){
  union { unsigned u; float f; } v; v.u = ((unsigned)(unsigned short)h)<<16; return v.f;
}
__device__ inline float sigm(float x){ return 1.f/(1.f+expf(-x)); }

// ============ K1: per-column partial sum / sumsq over obs rows ============
__global__ __launch_bounds__(256) void k_partial(const float* __restrict__ obs,
                                                 double* __restrict__ psum,
                                                 double* __restrict__ psq){
  int tid = threadIdx.x; int col = tid & 127; int rh = tid >> 7;
  double s = 0.0, q = 0.0;
  for (int r = blockIdx.x*2 + rh; r < N_ROWS; r += 2048){
    float v = obs[(size_t)r*D_DIM + col];
    s += (double)v; q += (double)v*(double)v;
  }
  __shared__ double ls[256], lq[256];
  ls[tid]=s; lq[tid]=q; __syncthreads();
  if (rh==0){
    psum[(size_t)blockIdx.x*128 + col] = ls[tid] + ls[tid+128];
    psq [(size_t)blockIdx.x*128 + col] = lq[tid] + lq[tid+128];
  }
}

// ============ K2: finalize Welford (chunk-combine) ============
__global__ __launch_bounds__(1024) void k_stats(const double* __restrict__ psum,
                                                const double* __restrict__ psq,
                                                const float* __restrict__ mean_obs,
                                                const float* __restrict__ welfS,
                                                const int* __restrict__ runcnt,
                                                float* __restrict__ outM, float* __restrict__ outS,
                                                float* __restrict__ wsM,  float* __restrict__ wsI){
  int tid = threadIdx.x; int col = tid & 127; int seg = tid >> 7; // 8 segs
  double s=0.0, q=0.0;
  for (int b=seg; b<1024; b+=8){ s += psum[(size_t)b*128+col]; q += psq[(size_t)b*128+col]; }
  __shared__ double ls[1024], lq[1024];
  ls[tid]=s; lq[tid]=q; __syncthreads();
  if (seg==0){
    for (int b=1;b<8;b++){ s += ls[b*128+col]; q += lq[b*128+col]; }
    double c0 = (double)runcnt[0];
    double Nn = (double)N_ROWS;
    double n  = c0 + Nn;
    double M0 = (double)mean_obs[col], S0 = (double)welfS[col];
    double mb = s / Nn;
    double delta = mb - M0;
    double M = M0 + delta * Nn / n;
    double M2b = q - Nn*mb*mb;
    double S = S0 + M2b + delta*delta*c0*Nn/n;
    double var = S / (n - 1.0);
    float inv = (float)(1.0/(sqrt(var)+1e-8));
    outM[col] = (float)M; outS[col] = (float)S;
    wsM[col]  = (float)M; wsI[col]  = inv;
  }
}

// ============ K3: pack weights into MFMA B-fragment order ============
__global__ void k_pack(const float* __restrict__ src, short* __restrict__ dst,
                       int C, int total, int mode){
  int idx = blockIdx.x*256 + threadIdx.x;
  if (idx >= total) return;
  int j = idx & 7, lane = (idx>>3)&63, kb = (idx>>9)&3, ct = idx>>11;
  int k = kb*32 + (lane>>4)*8 + j;
  int n = ct*16 + (lane&15);
  float w = src[(size_t)k*C + n];
  short h = f2bf(w);
  if (mode==2) h = f2bf(w - bf2f(h));
  dst[idx] = h;
}
__global__ void k_pack_head(const float* __restrict__ wa, const float* __restrict__ wb,
                            short* __restrict__ dst){
  int idx = blockIdx.x*256 + threadIdx.x;
  if (idx >= 2048) return;
  int j = idx & 7, lane = (idx>>3)&63, kb = (idx>>9)&3;
  int k = kb*32 + (lane>>4)*8 + j;
  int n = lane & 15;
  float w = (n<8) ? wa[(size_t)k*8 + n] : wb[(size_t)k*8 + (n-8)];
  dst[idx] = f2bf(w);
}

// ============ K3b: chunk schedule. Cut each row at first done >= 32k ============
__global__ void k_sched(const unsigned char* __restrict__ dones,
                        int* __restrict__ t0s, int* __restrict__ lens){
  int b = blockIdx.x*64 + threadIdx.x;
  if (b >= B_DIM) return;
  int cuts[NCHUNK+1]; cuts[0]=0; int nc=1;
  for (int k=1;k<NCHUNK;k++){
    int t = 32*k; int lo = cuts[nc-1]+1; if (t < lo) t = lo;
    while (t < T_DIM && dones[(size_t)t*B_DIM + b]==0) t++;
    if (t < T_DIM) cuts[nc++] = t;
  }
  for (int k=nc;k<=NCHUNK;k++) cuts[k] = T_DIM;
  for (int k=0;k<NCHUNK;k++){
    t0s[k*B_DIM+b] = cuts[k];
    lens[k*B_DIM+b] = cuts[k+1] - cuts[k];   // 0 for empty chunks (cuts[k]==256)
  }
}

// ============ K4: fused normalize -> emb(MFMA) -> relu -> xg(MFMA) ============
__global__ __launch_bounds__(256) void k_embxg(const float* __restrict__ obs,
                                               const float* __restrict__ wsM,
                                               const float* __restrict__ wsI,
                                               const short* __restrict__ Bemb,
                                               const float* __restrict__ b_emb,
                                               const short* __restrict__ BWi,
                                               short* __restrict__ xgpk){
  int tid=threadIdx.x, w=tid>>6, lane=tid&63, q=lane>>4, l=lane&15;
  int rt = blockIdx.x*4 + w;          // row tile (16 rows)
  int r0 = rt*16;
  __shared__ short embLds[4][16][136];

  bf16x8 A[4];
  #pragma unroll
  for (int kb=0; kb<4; kb++){
    int k0 = kb*32 + q*8;
    const f32x4* po = (const f32x4*)(obs + (size_t)(r0+l)*D_DIM + k0);
    f32x4 o0 = po[0], o1 = po[1];
    const f32x4* pm = (const f32x4*)(wsM + k0);
    const f32x4* pi = (const f32x4*)(wsI + k0);
    f32x4 m0 = pm[0], m1 = pm[1], i0 = pi[0], i1 = pi[1];
    bf16x8 a;
    a[0]=f2bf((o0[0]-m0[0])*i0[0]); a[1]=f2bf((o0[1]-m0[1])*i0[1]);
    a[2]=f2bf((o0[2]-m0[2])*i0[2]); a[3]=f2bf((o0[3]-m0[3])*i0[3]);
    a[4]=f2bf((o1[0]-m1[0])*i1[0]); a[5]=f2bf((o1[1]-m1[1])*i1[1]);
    a[6]=f2bf((o1[2]-m1[2])*i1[2]); a[7]=f2bf((o1[3]-m1[3])*i1[3]);
    A[kb]=a;
  }
  const bf16x8* BE = (const bf16x8*)Bemb;
  f32x4 accE[8];
  #pragma unroll
  for (int ct=0; ct<8; ct++){ f32x4 z = {0.f,0.f,0.f,0.f}; accE[ct]=z; }
  #pragma unroll
  for (int ct=0; ct<8; ct++)
    #pragma unroll
    for (int kb=0; kb<4; kb++)
      accE[ct] = __builtin_amdgcn_mfma_f32_16x16x32_bf16(A[kb], BE[(ct*4+kb)*64+lane], accE[ct], 0,0,0);
  #pragma unroll
  for (int ct=0; ct<8; ct++){
    int col = ct*16 + l;
    float bb = b_emb[col];
    #pragma unroll
    for (int r2=0;r2<4;r2++){
      float e = accE[ct][r2] + bb; e = e>0.f ? e : 0.f;
      embLds[w][q*4+r2][col] = f2bf(e);     // C/D layout -> A layout via (wave-private) LDS
    }
  }
  __syncthreads();
  bf16x8 A2[4];
  #pragma unroll
  for (int kb=0;kb<4;kb++) A2[kb] = *(const bf16x8*)&embLds[w][l][kb*32+q*8];
  const bf16x8* BW = (const bf16x8*)BWi;
  f32x4 accX[24];
  #pragma unroll
  for (int ct=0;ct<24;ct++){ f32x4 z = {0.f,0.f,0.f,0.f}; accX[ct]=z; }
  #pragma unroll
  for (int ct=0;ct<24;ct++)
    #pragma unroll
    for (int kb=0;kb<4;kb++)
      accX[ct] = __builtin_amdgcn_mfma_f32_16x16x32_bf16(A2[kb], BW[(ct*4+kb)*64+lane], accX[ct], 0,0,0);
  bf16x4* xg4 = (bf16x4*)xgpk;
  #pragma unroll
  for (int ct=0;ct<24;ct++){
    bf16x4 v;
    v[0]=f2bf(accX[ct][0]); v[1]=f2bf(accX[ct][1]);
    v[2]=f2bf(accX[ct][2]); v[3]=f2bf(accX[ct][3]);
    xg4[((size_t)rt*24+ct)*64 + lane] = v;   // packed C/D-frag order
  }
}

// ============ K5: segment-parallel GRU ============
// 256 blocks = 8 time-chunks x 32 batch-groups; block = chunk kk of rows [bt*16, bt*16+16).
// Wave w owns output cols [w*16, w*16+16) of each gate. ~32-55 iterations per block.
// lgkm-only barrier (no vmcnt drain) + 1-step xg/dones prefetch.
__global__ __launch_bounds__(512,2) void k_gru(const float* __restrict__ hidden,
                                             const unsigned char* __restrict__ dones,
                                             const short* __restrict__ xgpk,
                                             const short* __restrict__ Whhi,
                                             const short* __restrict__ Whlo,
                                             const float* __restrict__ bh,
                                             const int* __restrict__ t0s,
                                             const int* __restrict__ lens,
                                             short* __restrict__ yspk,
                                             float* __restrict__ h_last){
  int tid=threadIdx.x, w=tid>>6, lane=tid&63, q=lane>>4, l=lane&15;
  int tt = blockIdx.x; int kk = tt>>5; int bt = tt&31;
  __shared__ short hHi[2][16][136];
  __shared__ short hLo[2][16][136];
  __shared__ int Lsh;

  int t0r[4], lenr[4];
  #pragma unroll
  for (int r2=0;r2<4;r2++){
    int b = bt*16 + q*4 + r2;
    t0r[r2]  = t0s[kk*B_DIM + b];
    lenr[r2] = lens[kk*B_DIM + b];
  }
  if (tid==0) Lsh = 0;
  __syncthreads();
  int ml = max(max(lenr[0],lenr[1]), max(lenr[2],lenr[3]));
  atomicMax(&Lsh, ml);

  bf16x8 BH[3][4], BL[3][4];
  const bf16x8* ph = (const bf16x8*)Whhi;
  const bf16x8* pl = (const bf16x8*)Whlo;
  #pragma unroll
  for (int g=0; g<3; g++)
    #pragma unroll
    for (int kb=0; kb<4; kb++){
      int ct = g*8 + w;
      BH[g][kb] = ph[(ct*4+kb)*64+lane];
      BL[g][kb] = pl[(ct*4+kb)*64+lane];
    }
  float bhv[3];
  #pragma unroll
  for (int g=0;g<3;g++) bhv[g] = bh[g*128 + w*16 + l];
  float hv[4];
  #pragma unroll
  for (int r2=0;r2<4;r2++){
    int b = bt*16 + q*4 + r2;
    hv[r2] = (kk==0) ? hidden[(size_t)b*H_DIM + w*16 + l] : 0.f;
  }
  __syncthreads();
  int L = Lsh;

  // preload step-0 xg + dones
  short xr_c[4], xz_c[4], xn_c[4]; unsigned char dn_c[4];
  #pragma unroll
  for (int r2=0;r2<4;r2++){
    int tc = t0r[r2]; if (tc > 255) tc = 255;
    size_t o = (size_t)(tc*32+bt)*6144 + (size_t)w*256 + lane*4 + r2;
    xr_c[r2]=xgpk[o]; xz_c[r2]=xgpk[o+2048]; xn_c[r2]=xgpk[o+4096];
    dn_c[r2]=dones[(size_t)tc*B_DIM + bt*16 + q*4 + r2];
  }

  for (int i=0; i<L; i++){
    int buf = i & 1;
    #pragma unroll
    for (int r2=0;r2<4;r2++){
      if (i < lenr[r2] && dn_c[r2]) hv[r2] = 0.f;
      short hi = f2bf(hv[r2]);
      short lo = f2bf(hv[r2] - bf2f(hi));
      hHi[buf][q*4+r2][w*16+l] = hi;
      hLo[buf][q*4+r2][w*16+l] = lo;
    }
    // LDS-only barrier: no vmcnt drain -> ys stores + xg prefetch stay in flight
    __asm__ __volatile__("s_waitcnt lgkmcnt(0)\n\ts_barrier" ::: "memory");

    // prefetch step i+1 (clamped addresses; values gated by lenr next iter)
    short xr_n[4], xz_n[4], xn_n[4]; unsigned char dn_n[4];
    #pragma unroll
    for (int r2=0;r2<4;r2++){
      int tc = t0r[r2] + i + 1; if (tc > 255) tc = 255;
      size_t o = (size_t)(tc*32+bt)*6144 + (size_t)w*256 + lane*4 + r2;
      xr_n[r2]=xgpk[o]; xz_n[r2]=xgpk[o+2048]; xn_n[r2]=xgpk[o+4096];
      dn_n[r2]=dones[(size_t)tc*B_DIM + bt*16 + q*4 + r2];
    }

    bf16x8 Ah[4], Al[4];
    #pragma unroll
    for (int kb=0;kb<4;kb++){
      Ah[kb] = *(const bf16x8*)&hHi[buf][l][kb*32+q*8];
      Al[kb] = *(const bf16x8*)&hLo[buf][l][kb*32+q*8];
    }
    f32x4 acc[3];
    #pragma unroll
    for (int g=0;g<3;g++){
      f32x4 a0 = {0.f,0.f,0.f,0.f}, a1 = {0.f,0.f,0.f,0.f};
      #pragma unroll
      for (int kb=0;kb<2;kb++){
        a0 = __builtin_amdgcn_mfma_f32_16x16x32_bf16(Ah[kb], BH[g][kb], a0, 0,0,0);
        a0 = __builtin_amdgcn_mfma_f32_16x16x32_bf16(Ah[kb], BL[g][kb], a0, 0,0,0);
        a0 = __builtin_amdgcn_mfma_f32_16x16x32_bf16(Al[kb], BH[g][kb], a0, 0,0,0);
      }
      #pragma unroll
      for (int kb=2;kb<4;kb++){
        a1 = __builtin_amdgcn_mfma_f32_16x16x32_bf16(Ah[kb], BH[g][kb], a1, 0,0,0);
        a1 = __builtin_amdgcn_mfma_f32_16x16x32_bf16(Ah[kb], BL[g][kb], a1, 0,0,0);
        a1 = __builtin_amdgcn_mfma_f32_16x16x32_bf16(Al[kb], BH[g][kb], a1, 0,0,0);
      }
      acc[g] = a0 + a1;
    }
    #pragma unroll
    for (int r2=0;r2<4;r2++){
      float rg = sigm(bf2f(xr_c[r2]) + acc[0][r2] + bhv[0]);
      float zg = sigm(bf2f(xz_c[r2]) + acc[1][r2] + bhv[1]);
      float ng = tanhf(bf2f(xn_c[r2]) + rg*(acc[2][r2] + bhv[2]));
      float hn = (1.f - zg)*ng + zg*hv[r2];
      if (i < lenr[r2]){
        hv[r2] = hn;
        int t = t0r[r2] + i;
        yspk[(size_t)(t*32+bt)*2048 + (size_t)w*256 + lane*4 + r2] = f2bf(hn);
      }
    }
    #pragma unroll
    for (int r2=0;r2<4;r2++){
      xr_c[r2]=xr_n[r2]; xz_c[r2]=xz_n[r2]; xn_c[r2]=xn_n[r2]; dn_c[r2]=dn_n[r2];
    }
  }
  #pragma unroll
  for (int r2=0;r2<4;r2++)
    if (lenr[r2] > 0 && t0r[r2] + lenr[r2] == T_DIM)
      h_last[(size_t)(bt*16+q*4+r2)*H_DIM + w*16 + l] = hv[r2];
}

// ============ K6: act = relu(ys@W_act+b); alpha/beta = softplus(act@W+b)+1 ============
__global__ __launch_bounds__(256) void k_heads(const short* __restrict__ yspk,
                                               const short* __restrict__ Bact,
                                               const float* __restrict__ b_act,
                                               const short* __restrict__ Bhead,
                                               const float* __restrict__ b_alpha,
                                               const float* __restrict__ b_beta,
                                               float* __restrict__ alpha,
                                               float* __restrict__ beta){
  int tid=threadIdx.x, w=tid>>6, lane=tid&63, q=lane>>4, l=lane&15;
  size_t rt = (size_t)blockIdx.x*4 + w;
  __shared__ short tl[4][16][136];
  const bf16x4* ys4 = (const bf16x4*)yspk;
  #pragma unroll
  for (int ct=0; ct<8; ct++){
    bf16x4 v = ys4[(rt*8+ct)*64+lane];
    #pragma unroll
    for (int r2=0;r2<4;r2++) tl[w][q*4+r2][ct*16+l] = v[r2];
  }
  __syncthreads();
  bf16x8 A[4];
  #pragma unroll
  for (int kb=0;kb<4;kb++) A[kb] = *(const bf16x8*)&tl[w][l][kb*32+q*8];
  __syncthreads();
  const bf16x8* BA = (const bf16x8*)Bact;
  f32x4 accA[8];
  #pragma unroll
  for (int ct=0;ct<8;ct++){ f32x4 z = {0.f,0.f,0.f,0.f}; accA[ct]=z; }
  #pragma unroll
  for (int ct=0;ct<8;ct++)
    #pragma unroll
    for (int kb=0;kb<4;kb++)
      accA[ct] = __builtin_amdgcn_mfma_f32_16x16x32_bf16(A[kb], BA[(ct*4+kb)*64+lane], accA[ct], 0,0,0);
  #pragma unroll
  for (int ct=0;ct<8;ct++){
    int col = ct*16 + l;
    float bb = b_act[col];
    #pragma unroll
    for (int r2=0;r2<4;r2++){
      float e = accA[ct][r2] + bb; e = e>0.f ? e : 0.f;
      tl[w][q*4+r2][col] = f2bf(e);
    }
  }
  __syncthreads();
  bf16x8 A2[4];
  #pragma unroll
  for (int kb=0;kb<4;kb++) A2[kb] = *(const bf16x8*)&tl[w][l][kb*32+q*8];
  const bf16x8* BHd = (const bf16x8*)Bhead;
  f32x4 acc = {0.f,0.f,0.f,0.f};
  #pragma unroll
  for (int kb=0;kb<4;kb++)
    acc = __builtin_amdgcn_mfma_f32_16x16x32_bf16(A2[kb], BHd[kb*64+lane], acc, 0,0,0);
  float bb = (l<8) ? b_alpha[l] : b_beta[l-8];
  float* dst = (l<8) ? alpha : beta;
  int cc = (l<8) ? l : l-8;
  #pragma unroll
  for (int r2=0;r2<4;r2++){
    float u = acc[r2] + bb;
    float sp = fmaxf(u,0.f) + log1pf(expf(-fabsf(u)));
    dst[(rt*16 + q*4 + r2)*8 + cc] = sp + 1.f;
  }
}

// ================= host launcher =================
extern "C" void kernel_launch(void* const* d_in, const int* in_sizes, int n_in,
                              void* d_out, int out_size, void* d_ws, size_t ws_size,
                              hipStream_t stream){
  const float* hidden   = (const float*)d_in[0];
  const float* obs      = (const float*)d_in[1];
  const unsigned char* dones = (const unsigned char*)d_in[2];
  const float* mean_obs = (const float*)d_in[3];
  const float* welfS    = (const float*)d_in[4];
  const int*   runcnt   = (const int*)d_in[5];
  const float* W_emb = (const float*)d_in[6];
  const float* b_emb = (const float*)d_in[7];
  const float* Wi    = (const float*)d_in[8];
  const float* Wh    = (const float*)d_in[9];
  const float* bh    = (const float*)d_in[10];
  const float* W_act = (const float*)d_in[11];
  const float* b_act = (const float*)d_in[12];
  const float* W_al  = (const float*)d_in[13];
  const float* b_al  = (const float*)d_in[14];
  const float* W_be  = (const float*)d_in[15];
  const float* b_be  = (const float*)d_in[16];
  float* out = (float*)d_out;
  char*  ws  = (char*)d_ws;

  double* psum = (double*)(ws + OFF_PSUM);
  double* psq  = (double*)(ws + OFF_PSQ);
  float*  wsM  = (float*)(ws + OFF_STATM);
  float*  wsI  = (float*)(ws + OFF_STATI);
  short*  Bemb = (short*)(ws + OFF_WEMB);
  short*  BWi  = (short*)(ws + OFF_WI);
  short*  BWhh = (short*)(ws + OFF_WHHI);
  short*  BWhl = (short*)(ws + OFF_WHLO);
  short*  Bact = (short*)(ws + OFF_WACT);
  short*  Bhead= (short*)(ws + OFF_WHEAD);
  int*    t0s  = (int*)(ws + OFF_T0);
  int*    lns  = (int*)(ws + OFF_LEN);
  short*  xgpk = (short*)(ws + OFF_XG);
  short*  yspk = (short*)(ws + OFF_YS);

  k_partial<<<1024,256,0,stream>>>(obs, psum, psq);
  k_stats<<<1,1024,0,stream>>>(psum, psq, mean_obs, welfS, runcnt,
                               out+OUT_M, out+OUT_S, wsM, wsI);
  k_sched<<<8,64,0,stream>>>(dones, t0s, lns);
  k_pack<<<64, 256,0,stream>>>(W_emb, Bemb, 128, 16384, 0);
  k_pack<<<192,256,0,stream>>>(Wi,    BWi,  384, 49152, 0);
  k_pack<<<192,256,0,stream>>>(Wh,    BWhh, 384, 49152, 1);
  k_pack<<<192,256,0,stream>>>(Wh,    BWhl, 384, 49152, 2);
  k_pack<<<64, 256,0,stream>>>(W_act, Bact, 128, 16384, 0);
  k_pack_head<<<8,256,0,stream>>>(W_al, W_be, Bhead);
  k_embxg<<<2048,256,0,stream>>>(obs, wsM, wsI, Bemb, b_emb, BWi, xgpk);
  k_gru<<<256,512,0,stream>>>(hidden, dones, xgpk, BWhh, BWhl, bh, t0s, lns,
                              yspk, out + OUT_H);
  k_heads<<<2048,256,0,stream>>>(yspk, Bact, b_act, Bhead, b_al, b_be,
                                 out + OUT_ALPHA, out + OUT_BETA);
}

// Round 3
// 772.535 us; speedup vs baseline: 1.3275x; 1.3275x over previous
//
#include <hip/hip_runtime.h>

// ---------------- problem dims ----------------
#define T_DIM 256
#define B_DIM 512
#define D_DIM 128
#define H_DIM 128
#define A_DIM 8
#define N_ROWS (T_DIM*B_DIM)   // 131072 flattened rows
#define NT (N_ROWS/16)         // 8192 row tiles of 16
#define NWIN 8                 // time windows of 32 for the GRU

typedef __attribute__((ext_vector_type(4))) float f32x4;
typedef __attribute__((ext_vector_type(8))) short bf16x8;  // 8 bf16 in 4 VGPRs
typedef __attribute__((ext_vector_type(4))) short bf16x4;

// ---------------- workspace layout (bytes) ----------------
#define OFF_PSUM   0ull                    // 1024 blocks * 128 * f64 = 1 MB
#define OFF_PSQ    1048576ull              // 1 MB
#define OFF_STATM  2097152ull              // 128 f32
#define OFF_STATI  2097664ull              // 128 f32
#define OFF_WEMB   2098176ull              // 32768 B
#define OFF_WI     2130944ull              // 98304 B
#define OFF_WHHI   2229248ull              // 98304 B
#define OFF_WHLO   2327552ull              // 98304 B
#define OFF_WACT   2425856ull              // 32768 B
#define OFF_WHEAD  2458624ull              // 4096 B
#define OFF_TLO    2462720ull              // 8*32 int = 1024 B
#define OFF_UH     2463744ull              // 8*512 bytes = 4096 B
#define OFF_XG     4194304ull              // NT*24*64*4 bf16 = 96 MB (C/D-frag order)
#define OFF_YS     104857600ull            // NT*8*64*4 bf16 = 32 MB (C/D-frag order)
// total ws need: ~132 MB

// ---------------- output layout (f32 elements) ----------------
#define OUT_H      0          // h_last [512,128]
#define OUT_ALPHA  65536      // [256,512,8]
#define OUT_BETA   1114112    // [256,512,8]
#define OUT_M      2162688    // [128]
#define OUT_S      2162816    // [128]

__device__ inline short f2bf(float x){              // round-to-nearest-even f32->bf16
  union { float f; unsigned u; } v; v.f = x;
  unsigned r = v.u + 0x7FFFu + ((v.u>>16)&1u);
  return (short)(r>>16);
}
__device__ inline float bf2f(short h){
  union { unsigned u; float f; } v; v.u = ((unsigned)(unsigned short)h)<<16; return v.f;
}

// ============ K1: per-column partial sum / sumsq over obs rows ============
__global__ __launch_bounds__(256) void k_partial(const float* __restrict__ obs,
                                                 double* __restrict__ psum,
                                                 double* __restrict__ psq){
  int tid = threadIdx.x; int col = tid & 127; int rh = tid >> 7;
  double s = 0.0, q = 0.0;
  for (int r = blockIdx.x*2 + rh; r < N_ROWS; r += 2048){
    float v = obs[(size_t)r*D_DIM + col];
    s += (double)v; q += (double)v*(double)v;
  }
  __shared__ double ls[256], lq[256];
  ls[tid]=s; lq[tid]=q; __syncthreads();
  if (rh==0){
    psum[(size_t)blockIdx.x*128 + col] = ls[tid] + ls[tid+128];
    psq [(size_t)blockIdx.x*128 + col] = lq[tid] + lq[tid+128];
  }
}

// ============ K2: finalize Welford (chunk-combine) ============
__global__ __launch_bounds__(1024) void k_stats(const double* __restrict__ psum,
                                                const double* __restrict__ psq,
                                                const float* __restrict__ mean_obs,
                                                const float* __restrict__ welfS,
                                                const int* __restrict__ runcnt,
                                                float* __restrict__ outM, float* __restrict__ outS,
                                                float* __restrict__ wsM,  float* __restrict__ wsI){
  int tid = threadIdx.x; int col = tid & 127; int seg = tid >> 7; // 8 segs
  double s=0.0, q=0.0;
  for (int b=seg; b<1024; b+=8){ s += psum[(size_t)b*128+col]; q += psq[(size_t)b*128+col]; }
  __shared__ double ls[1024], lq[1024];
  ls[tid]=s; lq[tid]=q; __syncthreads();
  if (seg==0){
    for (int b=1;b<8;b++){ s += ls[b*128+col]; q += lq[b*128+col]; }
    double c0 = (double)runcnt[0];
    double Nn = (double)N_ROWS;
    double n  = c0 + Nn;
    double M0 = (double)mean_obs[col], S0 = (double)welfS[col];
    double mb = s / Nn;
    double delta = mb - M0;
    double M = M0 + delta * Nn / n;
    double M2b = q - Nn*mb*mb;
    double S = S0 + M2b + delta*delta*c0*Nn/n;
    double var = S / (n - 1.0);
    float inv = (float)(1.0/(sqrt(var)+1e-8));
    outM[col] = (float)M; outS[col] = (float)S;
    wsM[col]  = (float)M; wsI[col]  = inv;
  }
}

// ============ K3: all weight packs in ONE launch ============
// frag layout: ((ct*4+kb)*64+lane)*8+j holds W[k=kb*32+(lane>>4)*8+j][n=ct*16+(lane&15)]
// segments (elements): [0,16384) Bemb | [16384,65536) BWi | [65536,114688) BWhh(hi)
// | [114688,163840) BWhl(lo) | [163840,180224) Bact | [180224,182272) Bhead
__global__ void k_pack_all(const float* __restrict__ W_emb, const float* __restrict__ Wi,
                           const float* __restrict__ Wh,    const float* __restrict__ W_act,
                           const float* __restrict__ W_al,  const float* __restrict__ W_be,
                           short* __restrict__ Bemb, short* __restrict__ BWi,
                           short* __restrict__ BWhh, short* __restrict__ BWhl,
                           short* __restrict__ Bact, short* __restrict__ Bhead){
  int gidx = blockIdx.x*256 + threadIdx.x;
  if (gidx >= 182272) return;
  if (gidx >= 180224){
    int idx = gidx - 180224;
    int j = idx & 7, lane = (idx>>3)&63, kb = (idx>>9)&3;
    int k = kb*32 + (lane>>4)*8 + j;
    int n = lane & 15;
    float wv = (n<8) ? W_al[(size_t)k*8 + n] : W_be[(size_t)k*8 + (n-8)];
    Bhead[idx] = f2bf(wv);
    return;
  }
  const float* src; short* dst; int C; int mode; int idx;
  if (gidx < 16384)      { src=W_emb; dst=Bemb; C=128; mode=0; idx=gidx; }
  else if (gidx < 65536) { src=Wi;    dst=BWi;  C=384; mode=0; idx=gidx-16384; }
  else if (gidx < 114688){ src=Wh;    dst=BWhh; C=384; mode=1; idx=gidx-65536; }
  else if (gidx < 163840){ src=Wh;    dst=BWhl; C=384; mode=2; idx=gidx-114688; }
  else                   { src=W_act; dst=Bact; C=128; mode=0; idx=gidx-163840; }
  int j = idx & 7, lane = (idx>>3)&63, kb = (idx>>9)&3, ct = idx>>11;
  int k = kb*32 + (lane>>4)*8 + j;
  int n = ct*16 + (lane&15);
  float wv = src[(size_t)k*C + n];
  short h = f2bf(wv);
  if (mode==2) h = f2bf(wv - bf2f(h));
  dst[idx] = h;
}

// ============ K3b: window schedule ============
// For window k and row b: t0 = last t<=32k with done, usehid = (no done at all in [0,32k]).
// tlo[k][g] = min t0 over the 16 rows of group g.
__global__ __launch_bounds__(512) void k_sched(const unsigned char* __restrict__ dones,
                                               int* __restrict__ tlo,
                                               unsigned char* __restrict__ usehid){
  int k = blockIdx.x;         // 0..7
  int b = threadIdx.x;        // 0..511
  int t0 = 0, uh = 1;
  if (k > 0){
    for (int t = 32*k; t >= 0; t--){
      if (dones[(size_t)t*B_DIM + b]){ t0 = t; uh = 0; break; }
    }
  }
  usehid[k*B_DIM + b] = (unsigned char)uh;
  __shared__ int red[512];
  red[b] = t0; __syncthreads();
  if (b < 32){
    int m = red[b*16];
    #pragma unroll
    for (int i=1;i<16;i++) m = min(m, red[b*16+i]);
    tlo[k*32 + b] = m;
  }
}

// ============ K4: fused normalize -> emb(MFMA) -> relu -> xg(MFMA) ============
// 8192 blocks (one 16-row tile each) x 8 waves; wave w owns col-block w of emb and
// col-block w of each gate -> only 16 B-frags/wave (stay in VGPRs).
__global__ __launch_bounds__(512) void k_embxg(const float* __restrict__ obs,
                                               const float* __restrict__ wsM,
                                               const float* __restrict__ wsI,
                                               const short* __restrict__ Bemb,
                                               const float* __restrict__ b_emb,
                                               const short* __restrict__ BWi,
                                               short* __restrict__ xgpk){
  int tid=threadIdx.x, w=tid>>6, lane=tid&63, q=lane>>4, l=lane&15;
  int rt = blockIdx.x;
  int r0 = rt*16;
  __shared__ __align__(16) short obsL[16][136];
  __shared__ __align__(16) short embL[16][136];

  // stage normalized obs (bf16) into LDS: thread -> (row, 4-col segment)
  {
    int row = tid>>5, seg = tid&31;
    f32x4 o = *(const f32x4*)(obs + (size_t)(r0+row)*D_DIM + seg*4);
    f32x4 m = *(const f32x4*)(wsM + seg*4);
    f32x4 iv= *(const f32x4*)(wsI + seg*4);
    bf16x4 v;
    v[0]=f2bf((o[0]-m[0])*iv[0]); v[1]=f2bf((o[1]-m[1])*iv[1]);
    v[2]=f2bf((o[2]-m[2])*iv[2]); v[3]=f2bf((o[3]-m[3])*iv[3]);
    *(bf16x4*)&obsL[row][seg*4] = v;
  }
  __syncthreads();

  bf16x8 A[4];
  #pragma unroll
  for (int kb=0;kb<4;kb++) A[kb] = *(const bf16x8*)&obsL[l][kb*32+q*8];

  // emb: wave w computes col-tile ct=w
  const bf16x8* BE = (const bf16x8*)Bemb;
  f32x4 accE = {0.f,0.f,0.f,0.f};
  #pragma unroll
  for (int kb=0;kb<4;kb++)
    accE = __builtin_amdgcn_mfma_f32_16x16x32_bf16(A[kb], BE[(w*4+kb)*64+lane], accE, 0,0,0);
  {
    float bb = b_emb[w*16 + l];
    #pragma unroll
    for (int r2=0;r2<4;r2++){
      float e = accE[r2] + bb; e = e>0.f ? e : 0.f;
      embL[q*4+r2][w*16+l] = f2bf(e);
    }
  }
  __syncthreads();

  bf16x8 A2[4];
  #pragma unroll
  for (int kb=0;kb<4;kb++) A2[kb] = *(const bf16x8*)&embL[l][kb*32+q*8];

  // xg: wave w computes cts {w, 8+w, 16+w} (its 16-col slice of r,z,n)
  const bf16x8* BW = (const bf16x8*)BWi;
  bf16x4* xg4 = (bf16x4*)xgpk;
  #pragma unroll
  for (int g=0; g<3; g++){
    int ct = g*8 + w;
    f32x4 acc = {0.f,0.f,0.f,0.f};
    #pragma unroll
    for (int kb=0;kb<4;kb++)
      acc = __builtin_amdgcn_mfma_f32_16x16x32_bf16(A2[kb], BW[(ct*4+kb)*64+lane], acc, 0,0,0);
    bf16x4 v;
    v[0]=f2bf(acc[0]); v[1]=f2bf(acc[1]); v[2]=f2bf(acc[2]); v[3]=f2bf(acc[3]);
    xg4[((size_t)rt*24 + ct)*64 + lane] = v;
  }
}

// ============ K5: window-parallel GRU, time-aligned ============
// 256 blocks = 8 windows x 32 row-groups. Block runs global t from t_lo (warm-up,
// exact via done-resets) through its 32-step output window. Coalesced xg/ys.
__global__ __launch_bounds__(512,2) void k_gru(const float* __restrict__ hidden,
                                             const unsigned char* __restrict__ dones,
                                             const short* __restrict__ xgpk,
                                             const short* __restrict__ Whhi,
                                             const short* __restrict__ Whlo,
                                             const float* __restrict__ bh,
                                             const int* __restrict__ tlo,
                                             const unsigned char* __restrict__ usehid,
                                             short* __restrict__ yspk,
                                             float* __restrict__ h_last){
  int tid=threadIdx.x, w=tid>>6, lane=tid&63, q=lane>>4, l=lane&15;
  int kk = blockIdx.x >> 5, bt = blockIdx.x & 31;
  int t_out0 = kk*32;
  int t_end  = t_out0 + 32;
  int t_start = tlo[kk*32 + bt];

  __shared__ __align__(16) unsigned hPk[2][16][132];   // (hi<<16)|lo packed bf16 pair

  // Wh fragments, hi and lo parts (goal: resident in VGPRs)
  bf16x8 BH[3][4], BL[3][4];
  const bf16x8* ph = (const bf16x8*)Whhi;
  const bf16x8* pl = (const bf16x8*)Whlo;
  #pragma unroll
  for (int g=0;g<3;g++)
    #pragma unroll
    for (int kb=0;kb<4;kb++){
      int ct = g*8 + w;
      BH[g][kb] = ph[(ct*4+kb)*64+lane];
      BL[g][kb] = pl[(ct*4+kb)*64+lane];
    }
  float bhv[3];
  #pragma unroll
  for (int g=0;g<3;g++) bhv[g] = bh[g*128 + w*16 + l];

  float hv[4];
  #pragma unroll
  for (int r2=0;r2<4;r2++){
    int b = bt*16 + q*4 + r2;
    hv[r2] = usehid[kk*B_DIM + b] ? hidden[(size_t)b*H_DIM + w*16 + l] : 0.f;
  }

  const bf16x4* xg4 = (const bf16x4*)xgpk;
  bf16x4* ys4 = (bf16x4*)yspk;

  // preload step t_start
  size_t tile0 = (size_t)t_start*32 + bt;
  bf16x4 xr_c = xg4[(tile0*24 +      w)*64 + lane];
  bf16x4 xz_c = xg4[(tile0*24 +  8 + w)*64 + lane];
  bf16x4 xn_c = xg4[(tile0*24 + 16 + w)*64 + lane];
  unsigned dn_c = *(const unsigned*)(dones + (size_t)t_start*B_DIM + bt*16 + q*4);

  for (int t = t_start; t < t_end; t++){
    int buf = t & 1;
    // apply done-reset, split h into bf16 hi/lo, pack into LDS
    #pragma unroll
    for (int r2=0;r2<4;r2++){
      float hvv = ((dn_c >> (r2*8)) & 255u) ? 0.f : hv[r2];
      hv[r2] = hvv;
      short hi = f2bf(hvv);
      short lo = f2bf(hvv - bf2f(hi));
      hPk[buf][q*4+r2][w*16+l] = ((unsigned)(unsigned short)hi << 16) | (unsigned short)(unsigned short)lo;
    }
    // LDS-only barrier: don't drain vmcnt (ys stores + prefetches stay in flight)
    __asm__ __volatile__("s_waitcnt lgkmcnt(0)\n\ts_barrier" ::: "memory");

    // prefetch step t+1 (clamped; discarded on last iter)
    int tn = t+1; if (tn >= t_end) tn = t_end-1;
    size_t tile_n = (size_t)tn*32 + bt;
    bf16x4 xr_n = xg4[(tile_n*24 +      w)*64 + lane];
    bf16x4 xz_n = xg4[(tile_n*24 +  8 + w)*64 + lane];
    bf16x4 xn_n = xg4[(tile_n*24 + 16 + w)*64 + lane];
    unsigned dn_n = *(const unsigned*)(dones + (size_t)tn*B_DIM + bt*16 + q*4);

    // per-kb: read packed h row-frag, unpack hi/lo, 9 MFMAs (3 gates x 3 split terms)
    f32x4 acc0 = {0.f,0.f,0.f,0.f}, acc1 = {0.f,0.f,0.f,0.f}, acc2 = {0.f,0.f,0.f,0.f};
    #pragma unroll
    for (int kb=0;kb<4;kb++){
      const unsigned* pw = &hPk[buf][l][kb*32 + q*8];
      uint4 w0 = *(const uint4*)pw;
      uint4 w1 = *(const uint4*)(pw+4);
      union { unsigned u[4]; bf16x8 v; } Ah, Al;
      Ah.u[0] = (w0.x>>16) | (w0.y & 0xFFFF0000u);
      Ah.u[1] = (w0.z>>16) | (w0.w & 0xFFFF0000u);
      Ah.u[2] = (w1.x>>16) | (w1.y & 0xFFFF0000u);
      Ah.u[3] = (w1.z>>16) | (w1.w & 0xFFFF0000u);
      Al.u[0] = (w0.x & 0xFFFFu) | (w0.y<<16);
      Al.u[1] = (w0.z & 0xFFFFu) | (w0.w<<16);
      Al.u[2] = (w1.x & 0xFFFFu) | (w1.y<<16);
      Al.u[3] = (w1.z & 0xFFFFu) | (w1.w<<16);
      acc0 = __builtin_amdgcn_mfma_f32_16x16x32_bf16(Ah.v, BH[0][kb], acc0, 0,0,0);
      acc0 = __builtin_amdgcn_mfma_f32_16x16x32_bf16(Ah.v, BL[0][kb], acc0, 0,0,0);
      acc0 = __builtin_amdgcn_mfma_f32_16x16x32_bf16(Al.v, BH[0][kb], acc0, 0,0,0);
      acc1 = __builtin_amdgcn_mfma_f32_16x16x32_bf16(Ah.v, BH[1][kb], acc1, 0,0,0);
      acc1 = __builtin_amdgcn_mfma_f32_16x16x32_bf16(Ah.v, BL[1][kb], acc1, 0,0,0);
      acc1 = __builtin_amdgcn_mfma_f32_16x16x32_bf16(Al.v, BH[1][kb], acc1, 0,0,0);
      acc2 = __builtin_amdgcn_mfma_f32_16x16x32_bf16(Ah.v, BH[2][kb], acc2, 0,0,0);
      acc2 = __builtin_amdgcn_mfma_f32_16x16x32_bf16(Ah.v, BL[2][kb], acc2, 0,0,0);
      acc2 = __builtin_amdgcn_mfma_f32_16x16x32_bf16(Al.v, BH[2][kb], acc2, 0,0,0);
    }

    // gates (safe fast transcendentals: saturate at inf)
    #pragma unroll
    for (int r2=0;r2<4;r2++){
      float xr = bf2f(xr_c[r2]), xz = bf2f(xz_c[r2]), xn = bf2f(xn_c[r2]);
      float rg = 1.f/(1.f + __expf(-(xr + acc0[r2] + bhv[0])));
      float zg = 1.f/(1.f + __expf(-(xz + acc1[r2] + bhv[1])));
      float nu = xn + rg*(acc2[r2] + bhv[2]);
      float e2 = __expf(2.f*nu);
      float ng = 1.f - 2.f/(e2 + 1.f);          // tanh, inf-safe
      hv[r2] = (1.f - zg)*ng + zg*hv[r2];
    }
    if (t >= t_out0){
      bf16x4 yv;
      yv[0]=f2bf(hv[0]); yv[1]=f2bf(hv[1]); yv[2]=f2bf(hv[2]); yv[3]=f2bf(hv[3]);
      ys4[((size_t)(t*32+bt)*8 + w)*64 + lane] = yv;
    }
    xr_c = xr_n; xz_c = xz_n; xn_c = xn_n; dn_c = dn_n;
  }

  if (kk == NWIN-1){
    #pragma unroll
    for (int r2=0;r2<4;r2++)
      h_last[(size_t)(bt*16+q*4+r2)*H_DIM + w*16 + l] = hv[r2];
  }
}

// ============ K6: act = relu(ys@W_act+b); alpha/beta = softplus(act@W+b)+1 ============
__global__ __launch_bounds__(256) void k_heads(const short* __restrict__ yspk,
                                               const short* __restrict__ Bact,
                                               const float* __restrict__ b_act,
                                               const short* __restrict__ Bhead,
                                               const float* __restrict__ b_alpha,
                                               const float* __restrict__ b_beta,
                                               float* __restrict__ alpha,
                                               float* __restrict__ beta){
  int tid=threadIdx.x, w=tid>>6, lane=tid&63, q=lane>>4, l=lane&15;
  size_t rt = (size_t)blockIdx.x*4 + w;
  __shared__ __align__(16) short tl[4][16][136];
  const bf16x4* ys4 = (const bf16x4*)yspk;
  #pragma unroll
  for (int ct=0; ct<8; ct++){
    bf16x4 v = ys4[(rt*8+ct)*64+lane];
    #pragma unroll
    for (int r2=0;r2<4;r2++) tl[w][q*4+r2][ct*16+l] = v[r2];
  }
  __syncthreads();
  bf16x8 A[4];
  #pragma unroll
  for (int kb=0;kb<4;kb++) A[kb] = *(const bf16x8*)&tl[w][l][kb*32+q*8];
  __syncthreads();
  const bf16x8* BA = (const bf16x8*)Bact;
  f32x4 accA[8];
  #pragma unroll
  for (int ct=0;ct<8;ct++){ f32x4 z = {0.f,0.f,0.f,0.f}; accA[ct]=z; }
  #pragma unroll
  for (int ct=0;ct<8;ct++)
    #pragma unroll
    for (int kb=0;kb<4;kb++)
      accA[ct] = __builtin_amdgcn_mfma_f32_16x16x32_bf16(A[kb], BA[(ct*4+kb)*64+lane], accA[ct], 0,0,0);
  #pragma unroll
  for (int ct=0;ct<8;ct++){
    int col = ct*16 + l;
    float bb = b_act[col];
    #pragma unroll
    for (int r2=0;r2<4;r2++){
      float e = accA[ct][r2] + bb; e = e>0.f ? e : 0.f;
      tl[w][q*4+r2][col] = f2bf(e);
    }
  }
  __syncthreads();
  bf16x8 A2[4];
  #pragma unroll
  for (int kb=0;kb<4;kb++) A2[kb] = *(const bf16x8*)&tl[w][l][kb*32+q*8];
  const bf16x8* BHd = (const bf16x8*)Bhead;
  f32x4 acc = {0.f,0.f,0.f,0.f};
  #pragma unroll
  for (int kb=0;kb<4;kb++)
    acc = __builtin_amdgcn_mfma_f32_16x16x32_bf16(A2[kb], BHd[kb*64+lane], acc, 0,0,0);
  float bb = (l<8) ? b_alpha[l] : b_beta[l-8];
  float* dst = (l<8) ? alpha : beta;
  int cc = (l<8) ? l : l-8;
  #pragma unroll
  for (int r2=0;r2<4;r2++){
    float u = acc[r2] + bb;
    float sp = fmaxf(u,0.f) + log1pf(expf(-fabsf(u)));
    dst[(rt*16 + q*4 + r2)*8 + cc] = sp + 1.f;
  }
}

// ================= host launcher =================
extern "C" void kernel_launch(void* const* d_in, const int* in_sizes, int n_in,
                              void* d_out, int out_size, void* d_ws, size_t ws_size,
                              hipStream_t stream){
  const float* hidden   = (const float*)d_in[0];
  const float* obs      = (const float*)d_in[1];
  const unsigned char* dones = (const unsigned char*)d_in[2];
  const float* mean_obs = (const float*)d_in[3];
  const float* welfS    = (const float*)d_in[4];
  const int*   runcnt   = (const int*)d_in[5];
  const float* W_emb = (const float*)d_in[6];
  const float* b_emb = (const float*)d_in[7];
  const float* Wi    = (const float*)d_in[8];
  const float* Wh    = (const float*)d_in[9];
  const float* bh    = (const float*)d_in[10];
  const float* W_act = (const float*)d_in[11];
  const float* b_act = (const float*)d_in[12];
  const float* W_al  = (const float*)d_in[13];
  const float* b_al  = (const float*)d_in[14];
  const float* W_be  = (const float*)d_in[15];
  const float* b_be  = (const float*)d_in[16];
  float* out = (float*)d_out;
  char*  ws  = (char*)d_ws;

  double* psum = (double*)(ws + OFF_PSUM);
  double* psq  = (double*)(ws + OFF_PSQ);
  float*  wsM  = (float*)(ws + OFF_STATM);
  float*  wsI  = (float*)(ws + OFF_STATI);
  short*  Bemb = (short*)(ws + OFF_WEMB);
  short*  BWi  = (short*)(ws + OFF_WI);
  short*  BWhh = (short*)(ws + OFF_WHHI);
  short*  BWhl = (short*)(ws + OFF_WHLO);
  short*  Bact = (short*)(ws + OFF_WACT);
  short*  Bhead= (short*)(ws + OFF_WHEAD);
  int*    tlo  = (int*)(ws + OFF_TLO);
  unsigned char* uh = (unsigned char*)(ws + OFF_UH);
  short*  xgpk = (short*)(ws + OFF_XG);
  short*  yspk = (short*)(ws + OFF_YS);

  k_partial<<<1024,256,0,stream>>>(obs, psum, psq);
  k_stats<<<1,1024,0,stream>>>(psum, psq, mean_obs, welfS, runcnt,
                               out+OUT_M, out+OUT_S, wsM, wsI);
  k_sched<<<8,512,0,stream>>>(dones, tlo, uh);
  k_pack_all<<<712,256,0,stream>>>(W_emb, Wi, Wh, W_act, W_al, W_be,
                                   Bemb, BWi, BWhh, BWhl, Bact, Bhead);
  k_embxg<<<8192,512,0,stream>>>(obs, wsM, wsI, Bemb, b_emb, BWi, xgpk);
  k_gru<<<256,512,0,stream>>>(hidden, dones, xgpk, BWhh, BWhl, bh, tlo, uh,
                              yspk, out + OUT_H);
  k_heads<<<2048,256,0,stream>>>(yspk, Bact, b_act, Bhead, b_al, b_be,
                                 out + OUT_ALPHA, out + OUT_BETA);
}

// Round 5
// 700.113 us; speedup vs baseline: 1.4648x; 1.1034x over previous
//
#include <hip/hip_runtime.h>

// ---------------- problem dims ----------------
#define T_DIM 256
#define B_DIM 512
#define D_DIM 128
#define H_DIM 128
#define A_DIM 8
#define N_ROWS (T_DIM*B_DIM)   // 131072 flattened rows
#define NT (N_ROWS/16)         // 8192 row tiles of 16
#define NWIN 8                 // time windows of 32 for the GRU

typedef __attribute__((ext_vector_type(4))) float f32x4;
typedef __attribute__((ext_vector_type(8))) short bf16x8;     // 8 bf16 in 4 VGPRs
typedef __attribute__((ext_vector_type(4))) short bf16x4;
typedef __attribute__((ext_vector_type(8))) _Float16 f16x8;   // 8 f16 in 4 VGPRs

// ---------------- workspace layout (bytes) ----------------
#define OFF_PSUM   0ull
#define OFF_PSQ    1048576ull
#define OFF_STATM  2097152ull
#define OFF_STATI  2097664ull
#define OFF_WEMB   2098176ull              // 16384 el bf16
#define OFF_WI     2130944ull              // 49152 el bf16
#define OFF_WH     2229248ull              // 49152 el f16 (2-term split is on A side)
#define OFF_WACT   2425856ull              // 16384 el bf16
#define OFF_WHEAD  2458624ull              // 2048 el bf16
#define OFF_TLO    2462720ull              // 8*32 int
#define OFF_UH     2463744ull              // 8*512 bytes
#define OFF_XG     4194304ull              // 96 MB (C/D-frag order)
#define OFF_YS     104857600ull            // 32 MB (C/D-frag order)

// ---------------- output layout (f32 elements) ----------------
#define OUT_H      0
#define OUT_ALPHA  65536
#define OUT_BETA   1114112
#define OUT_M      2162688
#define OUT_S      2162816

__device__ inline short f2bf(float x){              // RNE f32->bf16
  union { float f; unsigned u; } v; v.f = x;
  unsigned r = v.u + 0x7FFFu + ((v.u>>16)&1u);
  return (short)(r>>16);
}
__device__ inline float bf2f(short h){
  union { unsigned u; float f; } v; v.u = ((unsigned)(unsigned short)h)<<16; return v.f;
}

// ============ K1: per-column partial sum / sumsq over obs rows ============
__global__ __launch_bounds__(256) void k_partial(const float* __restrict__ obs,
                                                 double* __restrict__ psum,
                                                 double* __restrict__ psq){
  int tid = threadIdx.x; int col = tid & 127; int rh = tid >> 7;
  double s = 0.0, q = 0.0;
  for (int r = blockIdx.x*2 + rh; r < N_ROWS; r += 2048){
    float v = obs[(size_t)r*D_DIM + col];
    s += (double)v; q += (double)v*(double)v;
  }
  __shared__ double ls[256], lq[256];
  ls[tid]=s; lq[tid]=q; __syncthreads();
  if (rh==0){
    psum[(size_t)blockIdx.x*128 + col] = ls[tid] + ls[tid+128];
    psq [(size_t)blockIdx.x*128 + col] = lq[tid] + lq[tid+128];
  }
}

// ============ K2: finalize Welford (chunk-combine) ============
__global__ __launch_bounds__(1024) void k_stats(const double* __restrict__ psum,
                                                const double* __restrict__ psq,
                                                const float* __restrict__ mean_obs,
                                                const float* __restrict__ welfS,
                                                const int* __restrict__ runcnt,
                                                float* __restrict__ outM, float* __restrict__ outS,
                                                float* __restrict__ wsM,  float* __restrict__ wsI){
  int tid = threadIdx.x; int col = tid & 127; int seg = tid >> 7;
  double s=0.0, q=0.0;
  for (int b=seg; b<1024; b+=8){ s += psum[(size_t)b*128+col]; q += psq[(size_t)b*128+col]; }
  __shared__ double ls[1024], lq[1024];
  ls[tid]=s; lq[tid]=q; __syncthreads();
  if (seg==0){
    for (int b=1;b<8;b++){ s += ls[b*128+col]; q += lq[b*128+col]; }
    double c0 = (double)runcnt[0];
    double Nn = (double)N_ROWS;
    double n  = c0 + Nn;
    double M0 = (double)mean_obs[col], S0 = (double)welfS[col];
    double mb = s / Nn;
    double delta = mb - M0;
    double M = M0 + delta * Nn / n;
    double M2b = q - Nn*mb*mb;
    double S = S0 + M2b + delta*delta*c0*Nn/n;
    double var = S / (n - 1.0);
    float inv = (float)(1.0/(sqrt(var)+1e-8));
    outM[col] = (float)M; outS[col] = (float)S;
    wsM[col]  = (float)M; wsI[col]  = inv;
  }
}

// ============ K3: all weight packs in ONE launch ============
// frag layout: ((ct*4+kb)*64+lane)*8+j holds W[k=kb*32+(lane>>4)*8+j][n=ct*16+(lane&15)]
__global__ void k_pack_all(const float* __restrict__ W_emb, const float* __restrict__ Wi,
                           const float* __restrict__ Wh,    const float* __restrict__ W_act,
                           const float* __restrict__ W_al,  const float* __restrict__ W_be,
                           short* __restrict__ Bemb, short* __restrict__ BWi,
                           short* __restrict__ BWh,  short* __restrict__ Bact,
                           short* __restrict__ Bhead){
  int gidx = blockIdx.x*256 + threadIdx.x;
  if (gidx >= 133120) return;
  if (gidx >= 131072){
    int idx = gidx - 131072;
    int j = idx & 7, lane = (idx>>3)&63, kb = (idx>>9)&3;
    int k = kb*32 + (lane>>4)*8 + j;
    int n = lane & 15;
    float wv = (n<8) ? W_al[(size_t)k*8 + n] : W_be[(size_t)k*8 + (n-8)];
    Bhead[idx] = f2bf(wv);
    return;
  }
  const float* src; short* dst; int C; int fmt; int idx;   // fmt 0=bf16 1=f16
  if (gidx < 16384)      { src=W_emb; dst=Bemb; C=128; fmt=0; idx=gidx; }
  else if (gidx < 65536) { src=Wi;    dst=BWi;  C=384; fmt=0; idx=gidx-16384; }
  else if (gidx < 114688){ src=Wh;    dst=BWh;  C=384; fmt=1; idx=gidx-65536; }
  else                   { src=W_act; dst=Bact; C=128; fmt=0; idx=gidx-114688; }
  int j = idx & 7, lane = (idx>>3)&63, kb = (idx>>9)&3, ct = idx>>11;
  int k = kb*32 + (lane>>4)*8 + j;
  int n = ct*16 + (lane&15);
  float wv = src[(size_t)k*C + n];
  short h;
  if (fmt==0) h = f2bf(wv);
  else { union { _Float16 hf; short s; } u; u.hf = (_Float16)wv; h = u.s; }
  dst[idx] = h;
}

// ============ K3b: window schedule ============
__global__ __launch_bounds__(512) void k_sched(const unsigned char* __restrict__ dones,
                                               int* __restrict__ tlo,
                                               unsigned char* __restrict__ usehid){
  int k = blockIdx.x;         // 0..7
  int b = threadIdx.x;        // 0..511
  int t0 = 0, uh = 1;
  if (k > 0){
    for (int t = 32*k; t >= 0; t--){
      if (dones[(size_t)t*B_DIM + b]){ t0 = t; uh = 0; break; }
    }
  }
  usehid[k*B_DIM + b] = (unsigned char)uh;
  __shared__ int red[512];
  red[b] = t0; __syncthreads();
  if (b < 32){
    int m = red[b*16];
    #pragma unroll
    for (int i=1;i<16;i++) m = min(m, red[b*16+i]);
    tlo[k*32 + b] = m;
  }
}

// ============ K4: fused normalize -> emb(MFMA) -> relu -> xg(MFMA) ============
__global__ __launch_bounds__(512) void k_embxg(const float* __restrict__ obs,
                                               const float* __restrict__ wsM,
                                               const float* __restrict__ wsI,
                                               const short* __restrict__ Bemb,
                                               const float* __restrict__ b_emb,
                                               const short* __restrict__ BWi,
                                               short* __restrict__ xgpk){
  int tid=threadIdx.x, w=tid>>6, lane=tid&63, q=lane>>4, l=lane&15;
  int rt = blockIdx.x;
  int r0 = rt*16;
  __shared__ __align__(16) short obsL[16][136];
  __shared__ __align__(16) short embL[16][136];

  {
    int row = tid>>5, seg = tid&31;
    f32x4 o = *(const f32x4*)(obs + (size_t)(r0+row)*D_DIM + seg*4);
    f32x4 m = *(const f32x4*)(wsM + seg*4);
    f32x4 iv= *(const f32x4*)(wsI + seg*4);
    bf16x4 v;
    v[0]=f2bf((o[0]-m[0])*iv[0]); v[1]=f2bf((o[1]-m[1])*iv[1]);
    v[2]=f2bf((o[2]-m[2])*iv[2]); v[3]=f2bf((o[3]-m[3])*iv[3]);
    *(bf16x4*)&obsL[row][seg*4] = v;
  }
  __syncthreads();

  bf16x8 A[4];
  #pragma unroll
  for (int kb=0;kb<4;kb++) A[kb] = *(const bf16x8*)&obsL[l][kb*32+q*8];

  const bf16x8* BE = (const bf16x8*)Bemb;
  f32x4 accE = {0.f,0.f,0.f,0.f};
  #pragma unroll
  for (int kb=0;kb<4;kb++)
    accE = __builtin_amdgcn_mfma_f32_16x16x32_bf16(A[kb], BE[(w*4+kb)*64+lane], accE, 0,0,0);
  {
    float bb = b_emb[w*16 + l];
    #pragma unroll
    for (int r2=0;r2<4;r2++){
      float e = accE[r2] + bb; e = e>0.f ? e : 0.f;
      embL[q*4+r2][w*16+l] = f2bf(e);
    }
  }
  __syncthreads();

  bf16x8 A2[4];
  #pragma unroll
  for (int kb=0;kb<4;kb++) A2[kb] = *(const bf16x8*)&embL[l][kb*32+q*8];

  const bf16x8* BW = (const bf16x8*)BWi;
  bf16x4* xg4 = (bf16x4*)xgpk;
  #pragma unroll
  for (int g=0; g<3; g++){
    int ct = g*8 + w;
    f32x4 acc = {0.f,0.f,0.f,0.f};
    #pragma unroll
    for (int kb=0;kb<4;kb++)
      acc = __builtin_amdgcn_mfma_f32_16x16x32_bf16(A2[kb], BW[(ct*4+kb)*64+lane], acc, 0,0,0);
    bf16x4 v;
    v[0]=f2bf(acc[0]); v[1]=f2bf(acc[1]); v[2]=f2bf(acc[2]); v[3]=f2bf(acc[3]);
    xg4[((size_t)rt*24 + ct)*64 + lane] = v;
  }
}

// ============ K5: window-parallel GRU, f16 2-term split ============
// h = hi(f16) + lo(f16); hg = (Ahi+Alo) @ f16(Wh) -> 24 MFMA/iter.
// 12 B-frags/wave (48 VGPRs) pinned COMPONENT-WISE (32-bit "+v" is the only
// form LLVM accepts) so the barrier's memory clobber can't re-load them.
__global__ __launch_bounds__(512,2) void k_gru(const float* __restrict__ hidden,
                                             const unsigned char* __restrict__ dones,
                                             const short* __restrict__ xgpk,
                                             const short* __restrict__ BWh,
                                             const float* __restrict__ bh,
                                             const int* __restrict__ tlo,
                                             const unsigned char* __restrict__ usehid,
                                             short* __restrict__ yspk,
                                             float* __restrict__ h_last){
  int tid=threadIdx.x, w=tid>>6, lane=tid&63, q=lane>>4, l=lane&15;
  int kk = blockIdx.x >> 5, bt = blockIdx.x & 31;
  int t_out0 = kk*32;
  int t_end  = t_out0 + 32;
  int t_start = tlo[kk*32 + bt];

  __shared__ __align__(16) _Float16 hHi[2][16][136];
  __shared__ __align__(16) _Float16 hLo[2][16][136];

  // B fragments: 3 gates x 4 kb, f16 Wh. Load once, pin per 32-bit component.
  unsigned bw[3][4][4];
  const uint4* pw = (const uint4*)BWh;
  #pragma unroll
  for (int g=0;g<3;g++)
    #pragma unroll
    for (int kb=0;kb<4;kb++){
      int ct = g*8 + w;
      uint4 t4 = pw[(ct*4+kb)*64+lane];
      bw[g][kb][0]=t4.x; bw[g][kb][1]=t4.y; bw[g][kb][2]=t4.z; bw[g][kb][3]=t4.w;
    }
  #pragma unroll
  for (int g=0;g<3;g++)
    #pragma unroll
    for (int kb=0;kb<4;kb++)
      #pragma unroll
      for (int i=0;i<4;i++)
        asm volatile("" : "+v"(bw[g][kb][i]));   // opaque SSA: no remat/re-load

  float bhv[3];
  #pragma unroll
  for (int g=0;g<3;g++) bhv[g] = bh[g*128 + w*16 + l];

  float hv[4];
  #pragma unroll
  for (int r2=0;r2<4;r2++){
    int b = bt*16 + q*4 + r2;
    hv[r2] = usehid[kk*B_DIM + b] ? hidden[(size_t)b*H_DIM + w*16 + l] : 0.f;
  }

  const bf16x4* xg4 = (const bf16x4*)xgpk;
  bf16x4* ys4 = (bf16x4*)yspk;

  size_t tile0 = (size_t)t_start*32 + bt;
  bf16x4 xr_c = xg4[(tile0*24 +      w)*64 + lane];
  bf16x4 xz_c = xg4[(tile0*24 +  8 + w)*64 + lane];
  bf16x4 xn_c = xg4[(tile0*24 + 16 + w)*64 + lane];
  unsigned dn_c = *(const unsigned*)(dones + (size_t)t_start*B_DIM + bt*16 + q*4);

  for (int t = t_start; t < t_end; t++){
    int buf = t & 1;
    // done-reset, exact f16 hi/lo split of h into LDS
    #pragma unroll
    for (int r2=0;r2<4;r2++){
      float hvv = ((dn_c >> (r2*8)) & 255u) ? 0.f : hv[r2];
      hv[r2] = hvv;
      _Float16 hi = (_Float16)hvv;
      _Float16 lo = (_Float16)(hvv - (float)hi);
      hHi[buf][q*4+r2][w*16+l] = hi;
      hLo[buf][q*4+r2][w*16+l] = lo;
    }
    // LDS-only barrier: don't drain vmcnt (ys stores + prefetches stay in flight)
    __asm__ __volatile__("s_waitcnt lgkmcnt(0)\n\ts_barrier" ::: "memory");

    // prefetch step t+1
    int tn = t+1; if (tn >= t_end) tn = t_end-1;
    size_t tile_n = (size_t)tn*32 + bt;
    bf16x4 xr_n = xg4[(tile_n*24 +      w)*64 + lane];
    bf16x4 xz_n = xg4[(tile_n*24 +  8 + w)*64 + lane];
    bf16x4 xn_n = xg4[(tile_n*24 + 16 + w)*64 + lane];
    unsigned dn_n = *(const unsigned*)(dones + (size_t)tn*B_DIM + bt*16 + q*4);

    f16x8 Ah[4], Al[4];
    #pragma unroll
    for (int kb=0;kb<4;kb++){
      Ah[kb] = *(const f16x8*)&hHi[buf][l][kb*32+q*8];
      Al[kb] = *(const f16x8*)&hLo[buf][l][kb*32+q*8];
    }
    f32x4 acc0 = {0.f,0.f,0.f,0.f}, acc1 = {0.f,0.f,0.f,0.f}, acc2 = {0.f,0.f,0.f,0.f};
    #pragma unroll
    for (int kb=0;kb<4;kb++){
      union { unsigned u[4]; f16x8 v; } B0, B1, B2;
      #pragma unroll
      for (int i=0;i<4;i++){ B0.u[i]=bw[0][kb][i]; B1.u[i]=bw[1][kb][i]; B2.u[i]=bw[2][kb][i]; }
      acc0 = __builtin_amdgcn_mfma_f32_16x16x32_f16(Ah[kb], B0.v, acc0, 0,0,0);
      acc0 = __builtin_amdgcn_mfma_f32_16x16x32_f16(Al[kb], B0.v, acc0, 0,0,0);
      acc1 = __builtin_amdgcn_mfma_f32_16x16x32_f16(Ah[kb], B1.v, acc1, 0,0,0);
      acc1 = __builtin_amdgcn_mfma_f32_16x16x32_f16(Al[kb], B1.v, acc1, 0,0,0);
      acc2 = __builtin_amdgcn_mfma_f32_16x16x32_f16(Ah[kb], B2.v, acc2, 0,0,0);
      acc2 = __builtin_amdgcn_mfma_f32_16x16x32_f16(Al[kb], B2.v, acc2, 0,0,0);
    }

    #pragma unroll
    for (int r2=0;r2<4;r2++){
      float xr = bf2f(xr_c[r2]), xz = bf2f(xz_c[r2]), xn = bf2f(xn_c[r2]);
      float rg = 1.f/(1.f + __expf(-(xr + acc0[r2] + bhv[0])));
      float zg = 1.f/(1.f + __expf(-(xz + acc1[r2] + bhv[1])));
      float nu = xn + rg*(acc2[r2] + bhv[2]);
      float e2 = __expf(2.f*nu);
      float ng = 1.f - 2.f/(e2 + 1.f);          // tanh, inf-safe
      hv[r2] = (1.f - zg)*ng + zg*hv[r2];
    }
    if (t >= t_out0){
      bf16x4 yv;
      yv[0]=f2bf(hv[0]); yv[1]=f2bf(hv[1]); yv[2]=f2bf(hv[2]); yv[3]=f2bf(hv[3]);
      ys4[((size_t)(t*32+bt)*8 + w)*64 + lane] = yv;
    }
    xr_c = xr_n; xz_c = xz_n; xn_c = xn_n; dn_c = dn_n;
  }

  if (kk == NWIN-1){
    #pragma unroll
    for (int r2=0;r2<4;r2++)
      h_last[(size_t)(bt*16+q*4+r2)*H_DIM + w*16 + l] = hv[r2];
  }
}

// ============ K6: act = relu(ys@W_act+b); alpha/beta = softplus(act@W+b)+1 ============
__global__ __launch_bounds__(256) void k_heads(const short* __restrict__ yspk,
                                               const short* __restrict__ Bact,
                                               const float* __restrict__ b_act,
                                               const short* __restrict__ Bhead,
                                               const float* __restrict__ b_alpha,
                                               const float* __restrict__ b_beta,
                                               float* __restrict__ alpha,
                                               float* __restrict__ beta){
  int tid=threadIdx.x, w=tid>>6, lane=tid&63, q=lane>>4, l=lane&15;
  size_t rt = (size_t)blockIdx.x*4 + w;
  __shared__ __align__(16) short tl[4][16][136];
  const bf16x4* ys4 = (const bf16x4*)yspk;
  #pragma unroll
  for (int ct=0; ct<8; ct++){
    bf16x4 v = ys4[(rt*8+ct)*64+lane];
    #pragma unroll
    for (int r2=0;r2<4;r2++) tl[w][q*4+r2][ct*16+l] = v[r2];
  }
  __syncthreads();
  bf16x8 A[4];
  #pragma unroll
  for (int kb=0;kb<4;kb++) A[kb] = *(const bf16x8*)&tl[w][l][kb*32+q*8];
  __syncthreads();
  const bf16x8* BA = (const bf16x8*)Bact;
  f32x4 accA[8];
  #pragma unroll
  for (int ct=0;ct<8;ct++){ f32x4 z = {0.f,0.f,0.f,0.f}; accA[ct]=z; }
  #pragma unroll
  for (int ct=0;ct<8;ct++)
    #pragma unroll
    for (int kb=0;kb<4;kb++)
      accA[ct] = __builtin_amdgcn_mfma_f32_16x16x32_bf16(A[kb], BA[(ct*4+kb)*64+lane], accA[ct], 0,0,0);
  #pragma unroll
  for (int ct=0;ct<8;ct++){
    int col = ct*16 + l;
    float bb = b_act[col];
    #pragma unroll
    for (int r2=0;r2<4;r2++){
      float e = accA[ct][r2] + bb; e = e>0.f ? e : 0.f;
      tl[w][q*4+r2][col] = f2bf(e);
    }
  }
  __syncthreads();
  bf16x8 A2[4];
  #pragma unroll
  for (int kb=0;kb<4;kb++) A2[kb] = *(const bf16x8*)&tl[w][l][kb*32+q*8];
  const bf16x8* BHd = (const bf16x8*)Bhead;
  f32x4 acc = {0.f,0.f,0.f,0.f};
  #pragma unroll
  for (int kb=0;kb<4;kb++)
    acc = __builtin_amdgcn_mfma_f32_16x16x32_bf16(A2[kb], BHd[kb*64+lane], acc, 0,0,0);
  float bb = (l<8) ? b_alpha[l] : b_beta[l-8];
  float* dst = (l<8) ? alpha : beta;
  int cc = (l<8) ? l : l-8;
  #pragma unroll
  for (int r2=0;r2<4;r2++){
    float u = acc[r2] + bb;
    float sp = fmaxf(u,0.f) + log1pf(expf(-fabsf(u)));
    dst[(rt*16 + q*4 + r2)*8 + cc] = sp + 1.f;
  }
}

// ================= host launcher =================
extern "C" void kernel_launch(void* const* d_in, const int* in_sizes, int n_in,
                              void* d_out, int out_size, void* d_ws, size_t ws_size,
                              hipStream_t stream){
  const float* hidden   = (const float*)d_in[0];
  const float* obs      = (const float*)d_in[1];
  const unsigned char* dones = (const unsigned char*)d_in[2];
  const float* mean_obs = (const float*)d_in[3];
  const float* welfS    = (const float*)d_in[4];
  const int*   runcnt   = (const int*)d_in[5];
  const float* W_emb = (const float*)d_in[6];
  const float* b_emb = (const float*)d_in[7];
  const float* Wi    = (const float*)d_in[8];
  const float* Wh    = (const float*)d_in[9];
  const float* bh    = (const float*)d_in[10];
  const float* W_act = (const float*)d_in[11];
  const float* b_act = (const float*)d_in[12];
  const float* W_al  = (const float*)d_in[13];
  const float* b_al  = (const float*)d_in[14];
  const float* W_be  = (const float*)d_in[15];
  const float* b_be  = (const float*)d_in[16];
  float* out = (float*)d_out;
  char*  ws  = (char*)d_ws;

  double* psum = (double*)(ws + OFF_PSUM);
  double* psq  = (double*)(ws + OFF_PSQ);
  float*  wsM  = (float*)(ws + OFF_STATM);
  float*  wsI  = (float*)(ws + OFF_STATI);
  short*  Bemb = (short*)(ws + OFF_WEMB);
  short*  BWi  = (short*)(ws + OFF_WI);
  short*  BWh  = (short*)(ws + OFF_WH);
  short*  Bact = (short*)(ws + OFF_WACT);
  short*  Bhead= (short*)(ws + OFF_WHEAD);
  int*    tlo  = (int*)(ws + OFF_TLO);
  unsigned char* uh = (unsigned char*)(ws + OFF_UH);
  short*  xgpk = (short*)(ws + OFF_XG);
  short*  yspk = (short*)(ws + OFF_YS);

  k_partial<<<1024,256,0,stream>>>(obs, psum, psq);
  k_stats<<<1,1024,0,stream>>>(psum, psq, mean_obs, welfS, runcnt,
                               out+OUT_M, out+OUT_S, wsM, wsI);
  k_sched<<<8,512,0,stream>>>(dones, tlo, uh);
  k_pack_all<<<520,256,0,stream>>>(W_emb, Wi, Wh, W_act, W_al, W_be,
                                   Bemb, BWi, BWh, Bact, Bhead);
  k_embxg<<<8192,512,0,stream>>>(obs, wsM, wsI, Bemb, b_emb, BWi, xgpk);
  k_gru<<<256,512,0,stream>>>(hidden, dones, xgpk, BWh, bh, tlo, uh,
                              yspk, out + OUT_H);
  k_heads<<<2048,256,0,stream>>>(yspk, Bact, b_act, Bhead, b_al, b_be,
                                 out + OUT_ALPHA, out + OUT_BETA);
}

// Round 6
// 663.759 us; speedup vs baseline: 1.5451x; 1.0548x over previous
//
#include <hip/hip_runtime.h>

// ---------------- problem dims ----------------
#define T_DIM 256
#define B_DIM 512
#define D_DIM 128
#define H_DIM 128
#define A_DIM 8
#define N_ROWS (T_DIM*B_DIM)   // 131072 flattened rows
#define NT (N_ROWS/16)         // 8192 row tiles of 16
#define NWIN 8                 // time windows of 32 for the GRU

typedef __attribute__((ext_vector_type(4))) float f32x4;
typedef __attribute__((ext_vector_type(8))) short bf16x8;     // 8 bf16 in 4 VGPRs
typedef __attribute__((ext_vector_type(4))) short bf16x4;
typedef __attribute__((ext_vector_type(8))) _Float16 f16x8;   // 8 f16 in 4 VGPRs

// ---------------- workspace layout (bytes) ----------------
#define OFF_PSUM   0ull
#define OFF_PSQ    1048576ull
#define OFF_STATM  2097152ull
#define OFF_STATI  2097664ull
#define OFF_WEMB   2098176ull              // 16384 el bf16
#define OFF_WI     2130944ull              // 49152 el bf16
#define OFF_WH     2229248ull              // 49152 el f16
#define OFF_WACT   2425856ull              // 16384 el bf16
#define OFF_WHEAD  2458624ull              // 2048 el bf16
#define OFF_TLO    2462720ull              // 8*32 int
#define OFF_UH     2463744ull              // 8*512 bytes
#define OFF_XG     4194304ull              // 96 MB (C/D-frag order)
#define OFF_YS     104857600ull            // 32 MB (C/D-frag order)

// ---------------- output layout (f32 elements) ----------------
#define OUT_H      0
#define OUT_ALPHA  65536
#define OUT_BETA   1114112
#define OUT_M      2162688
#define OUT_S      2162816

__device__ inline short f2bf(float x){              // RNE f32->bf16
  union { float f; unsigned u; } v; v.f = x;
  unsigned r = v.u + 0x7FFFu + ((v.u>>16)&1u);
  return (short)(r>>16);
}
__device__ inline float bf2f(short h){
  union { unsigned u; float f; } v; v.u = ((unsigned)(unsigned short)h)<<16; return v.f;
}

// ============ K1: per-column partial sum / sumsq over obs rows ============
__global__ __launch_bounds__(256) void k_partial(const float* __restrict__ obs,
                                                 double* __restrict__ psum,
                                                 double* __restrict__ psq){
  int tid = threadIdx.x; int col = tid & 127; int rh = tid >> 7;
  double s = 0.0, q = 0.0;
  for (int r = blockIdx.x*2 + rh; r < N_ROWS; r += 2048){
    float v = obs[(size_t)r*D_DIM + col];
    s += (double)v; q += (double)v*(double)v;
  }
  __shared__ double ls[256], lq[256];
  ls[tid]=s; lq[tid]=q; __syncthreads();
  if (rh==0){
    psum[(size_t)blockIdx.x*128 + col] = ls[tid] + ls[tid+128];
    psq [(size_t)blockIdx.x*128 + col] = lq[tid] + lq[tid+128];
  }
}

// ============ K2: finalize Welford (chunk-combine) ============
__global__ __launch_bounds__(1024) void k_stats(const double* __restrict__ psum,
                                                const double* __restrict__ psq,
                                                const float* __restrict__ mean_obs,
                                                const float* __restrict__ welfS,
                                                const int* __restrict__ runcnt,
                                                float* __restrict__ outM, float* __restrict__ outS,
                                                float* __restrict__ wsM,  float* __restrict__ wsI){
  int tid = threadIdx.x; int col = tid & 127; int seg = tid >> 7;
  double s=0.0, q=0.0;
  for (int b=seg; b<1024; b+=8){ s += psum[(size_t)b*128+col]; q += psq[(size_t)b*128+col]; }
  __shared__ double ls[1024], lq[1024];
  ls[tid]=s; lq[tid]=q; __syncthreads();
  if (seg==0){
    for (int b=1;b<8;b++){ s += ls[b*128+col]; q += lq[b*128+col]; }
    double c0 = (double)runcnt[0];
    double Nn = (double)N_ROWS;
    double n  = c0 + Nn;
    double M0 = (double)mean_obs[col], S0 = (double)welfS[col];
    double mb = s / Nn;
    double delta = mb - M0;
    double M = M0 + delta * Nn / n;
    double M2b = q - Nn*mb*mb;
    double S = S0 + M2b + delta*delta*c0*Nn/n;
    double var = S / (n - 1.0);
    float inv = (float)(1.0/(sqrt(var)+1e-8));
    outM[col] = (float)M; outS[col] = (float)S;
    wsM[col]  = (float)M; wsI[col]  = inv;
  }
}

// ============ K3: all weight packs in ONE launch ============
// frag layout: ((ct*4+kb)*64+lane)*8+j holds W[k=kb*32+(lane>>4)*8+j][n=ct*16+(lane&15)]
__global__ void k_pack_all(const float* __restrict__ W_emb, const float* __restrict__ Wi,
                           const float* __restrict__ Wh,    const float* __restrict__ W_act,
                           const float* __restrict__ W_al,  const float* __restrict__ W_be,
                           short* __restrict__ Bemb, short* __restrict__ BWi,
                           short* __restrict__ BWh,  short* __restrict__ Bact,
                           short* __restrict__ Bhead){
  int gidx = blockIdx.x*256 + threadIdx.x;
  if (gidx >= 133120) return;
  if (gidx >= 131072){
    int idx = gidx - 131072;
    int j = idx & 7, lane = (idx>>3)&63, kb = (idx>>9)&3;
    int k = kb*32 + (lane>>4)*8 + j;
    int n = lane & 15;
    float wv = (n<8) ? W_al[(size_t)k*8 + n] : W_be[(size_t)k*8 + (n-8)];
    Bhead[idx] = f2bf(wv);
    return;
  }
  const float* src; short* dst; int C; int fmt; int idx;   // fmt 0=bf16 1=f16
  if (gidx < 16384)      { src=W_emb; dst=Bemb; C=128; fmt=0; idx=gidx; }
  else if (gidx < 65536) { src=Wi;    dst=BWi;  C=384; fmt=0; idx=gidx-16384; }
  else if (gidx < 114688){ src=Wh;    dst=BWh;  C=384; fmt=1; idx=gidx-65536; }
  else                   { src=W_act; dst=Bact; C=128; fmt=0; idx=gidx-114688; }
  int j = idx & 7, lane = (idx>>3)&63, kb = (idx>>9)&3, ct = idx>>11;
  int k = kb*32 + (lane>>4)*8 + j;
  int n = ct*16 + (lane&15);
  float wv = src[(size_t)k*C + n];
  short h;
  if (fmt==0) h = f2bf(wv);
  else { union { _Float16 hf; short s; } u; u.hf = (_Float16)wv; h = u.s; }
  dst[idx] = h;
}

// ============ K3b: window schedule ============
__global__ __launch_bounds__(512) void k_sched(const unsigned char* __restrict__ dones,
                                               int* __restrict__ tlo,
                                               unsigned char* __restrict__ usehid){
  int k = blockIdx.x;         // 0..7
  int b = threadIdx.x;        // 0..511
  int t0 = 0, uh = 1;
  if (k > 0){
    for (int t = 32*k; t >= 0; t--){
      if (dones[(size_t)t*B_DIM + b]){ t0 = t; uh = 0; break; }
    }
  }
  usehid[k*B_DIM + b] = (unsigned char)uh;
  __shared__ int red[512];
  red[b] = t0; __syncthreads();
  if (b < 32){
    int m = red[b*16];
    #pragma unroll
    for (int i=1;i<16;i++) m = min(m, red[b*16+i]);
    tlo[k*32 + b] = m;
  }
}

// ============ K4: fused normalize -> emb(MFMA) -> relu -> xg(MFMA) ============
__global__ __launch_bounds__(512) void k_embxg(const float* __restrict__ obs,
                                               const float* __restrict__ wsM,
                                               const float* __restrict__ wsI,
                                               const short* __restrict__ Bemb,
                                               const float* __restrict__ b_emb,
                                               const short* __restrict__ BWi,
                                               short* __restrict__ xgpk){
  int tid=threadIdx.x, w=tid>>6, lane=tid&63, q=lane>>4, l=lane&15;
  int rt = blockIdx.x;
  int r0 = rt*16;
  __shared__ __align__(16) short obsL[16][136];
  __shared__ __align__(16) short embL[16][136];

  {
    int row = tid>>5, seg = tid&31;
    f32x4 o = *(const f32x4*)(obs + (size_t)(r0+row)*D_DIM + seg*4);
    f32x4 m = *(const f32x4*)(wsM + seg*4);
    f32x4 iv= *(const f32x4*)(wsI + seg*4);
    bf16x4 v;
    v[0]=f2bf((o[0]-m[0])*iv[0]); v[1]=f2bf((o[1]-m[1])*iv[1]);
    v[2]=f2bf((o[2]-m[2])*iv[2]); v[3]=f2bf((o[3]-m[3])*iv[3]);
    *(bf16x4*)&obsL[row][seg*4] = v;
  }
  __syncthreads();

  bf16x8 A[4];
  #pragma unroll
  for (int kb=0;kb<4;kb++) A[kb] = *(const bf16x8*)&obsL[l][kb*32+q*8];

  const bf16x8* BE = (const bf16x8*)Bemb;
  f32x4 accE = {0.f,0.f,0.f,0.f};
  #pragma unroll
  for (int kb=0;kb<4;kb++)
    accE = __builtin_amdgcn_mfma_f32_16x16x32_bf16(A[kb], BE[(w*4+kb)*64+lane], accE, 0,0,0);
  {
    float bb = b_emb[w*16 + l];
    #pragma unroll
    for (int r2=0;r2<4;r2++){
      float e = accE[r2] + bb; e = e>0.f ? e : 0.f;
      embL[q*4+r2][w*16+l] = f2bf(e);
    }
  }
  __syncthreads();

  bf16x8 A2[4];
  #pragma unroll
  for (int kb=0;kb<4;kb++) A2[kb] = *(const bf16x8*)&embL[l][kb*32+q*8];

  const bf16x8* BW = (const bf16x8*)BWi;
  bf16x4* xg4 = (bf16x4*)xgpk;
  #pragma unroll
  for (int g=0; g<3; g++){
    int ct = g*8 + w;
    f32x4 acc = {0.f,0.f,0.f,0.f};
    #pragma unroll
    for (int kb=0;kb<4;kb++)
      acc = __builtin_amdgcn_mfma_f32_16x16x32_bf16(A2[kb], BW[(ct*4+kb)*64+lane], acc, 0,0,0);
    bf16x4 v;
    v[0]=f2bf(acc[0]); v[1]=f2bf(acc[1]); v[2]=f2bf(acc[2]); v[3]=f2bf(acc[3]);
    xg4[((size_t)rt*24 + ct)*64 + lane] = v;
  }
}

// ============ K5: window-parallel GRU, single f16, lean loop ============
// 12 MFMA/iter, 12 B-frags (48 VGPRs) with IN-LOOP pins; running pointers;
// lgkm-only barrier. Target: B-frags finally register-resident.
__global__ __launch_bounds__(512,1) void k_gru(const float* __restrict__ hidden,
                                             const unsigned char* __restrict__ dones,
                                             const short* __restrict__ xgpk,
                                             const short* __restrict__ BWh,
                                             const float* __restrict__ bh,
                                             const int* __restrict__ tlo,
                                             const unsigned char* __restrict__ usehid,
                                             short* __restrict__ yspk,
                                             float* __restrict__ h_last){
  int tid=threadIdx.x, w=tid>>6, lane=tid&63, q=lane>>4, l=lane&15;
  int kk = blockIdx.x >> 5, bt = blockIdx.x & 31;
  int t_out0 = kk*32;
  int t_end  = t_out0 + 32;
  int t_start = tlo[kk*32 + bt];

  __shared__ __align__(16) _Float16 hF[2][16][136];   // 8704 B

  // 12 B-fragments (3 gates x 4 kb), f16 Wh, as 48 pinned 32-bit components
  unsigned bw[12][4];
  {
    const uint4* pw4 = (const uint4*)BWh;
    #pragma unroll
    for (int g=0;g<3;g++)
      #pragma unroll
      for (int kb=0;kb<4;kb++){
        uint4 t4 = pw4[((g*8+w)*4+kb)*64+lane];
        bw[g*4+kb][0]=t4.x; bw[g*4+kb][1]=t4.y; bw[g*4+kb][2]=t4.z; bw[g*4+kb][3]=t4.w;
      }
  }

  float bhv[3];
  #pragma unroll
  for (int g=0;g<3;g++) bhv[g] = bh[g*128 + w*16 + l];

  float hv[4];
  #pragma unroll
  for (int r2=0;r2<4;r2++){
    int b = bt*16 + q*4 + r2;
    hv[r2] = usehid[kk*B_DIM + b] ? hidden[(size_t)b*H_DIM + w*16 + l] : 0.f;
  }

  // running pointers (uniform per-iter strides; no per-iter 64-bit muls)
  const bf16x4* xgt = (const bf16x4*)xgpk + (((size_t)t_start*32 + bt)*24 + w)*64 + lane;
  const unsigned char* dnp = dones + (size_t)t_start*B_DIM + bt*16 + q*4;
  bf16x4* yst = (bf16x4*)yspk + (((size_t)t_start*32 + bt)*8 + w)*64 + lane;

  bf16x4 xr_c = xgt[0], xz_c = xgt[512], xn_c = xgt[1024];   // gate stride 8*64
  unsigned dn_c = *(const unsigned*)dnp;

  for (int t = t_start; t < t_end; t++){
    int buf = t & 1;
    #pragma unroll
    for (int r2=0;r2<4;r2++){
      float hvv = ((dn_c >> (r2*8)) & 255u) ? 0.f : hv[r2];
      hv[r2] = hvv;
      hF[buf][q*4+r2][w*16+l] = (_Float16)hvv;
    }
    // LDS-only barrier: no vmcnt drain (ys stores + prefetches stay in flight)
    __asm__ __volatile__("s_waitcnt lgkmcnt(0)\n\ts_barrier" ::: "memory");

    // in-loop pin: forces B components VGPR-resident across the barrier
    #pragma unroll
    for (int f=0; f<12; f++)
      #pragma unroll
      for (int i=0; i<4; i++)
        asm volatile("" : "+v"(bw[f][i]));

    // advance + prefetch step t+1 (advance 0 on last iter -> no OOB)
    int adv = (t+1 < t_end) ? 1 : 0;
    xgt += (size_t)adv * 49152;       // 32 tiles * 24 * 64
    dnp += adv * B_DIM;
    bf16x4 xr_n = xgt[0], xz_n = xgt[512], xn_n = xgt[1024];
    unsigned dn_n = *(const unsigned*)dnp;

    f16x8 Ah[4];
    #pragma unroll
    for (int kb=0;kb<4;kb++) Ah[kb] = *(const f16x8*)&hF[buf][l][kb*32+q*8];

    f32x4 acc0 = {0.f,0.f,0.f,0.f}, acc1 = {0.f,0.f,0.f,0.f}, acc2 = {0.f,0.f,0.f,0.f};
    #pragma unroll
    for (int kb=0;kb<4;kb++){
      union { unsigned u[4]; f16x8 v; } B0, B1, B2;
      #pragma unroll
      for (int i=0;i<4;i++){ B0.u[i]=bw[kb][i]; B1.u[i]=bw[4+kb][i]; B2.u[i]=bw[8+kb][i]; }
      acc0 = __builtin_amdgcn_mfma_f32_16x16x32_f16(Ah[kb], B0.v, acc0, 0,0,0);
      acc1 = __builtin_amdgcn_mfma_f32_16x16x32_f16(Ah[kb], B1.v, acc1, 0,0,0);
      acc2 = __builtin_amdgcn_mfma_f32_16x16x32_f16(Ah[kb], B2.v, acc2, 0,0,0);
    }

    #pragma unroll
    for (int r2=0;r2<4;r2++){
      float xr = bf2f(xr_c[r2]), xz = bf2f(xz_c[r2]), xn = bf2f(xn_c[r2]);
      float rg = 1.f/(1.f + __expf(-(xr + acc0[r2] + bhv[0])));
      float zg = 1.f/(1.f + __expf(-(xz + acc1[r2] + bhv[1])));
      float nu = xn + rg*(acc2[r2] + bhv[2]);
      float e2 = __expf(2.f*nu);
      float ng = 1.f - 2.f/(e2 + 1.f);          // tanh, inf-safe
      hv[r2] = (1.f - zg)*ng + zg*hv[r2];
    }
    if (t >= t_out0){
      bf16x4 yv;
      yv[0]=f2bf(hv[0]); yv[1]=f2bf(hv[1]); yv[2]=f2bf(hv[2]); yv[3]=f2bf(hv[3]);
      *yst = yv;
    }
    yst += 16384;                     // 32 tiles * 8 * 64 (advance always; deref gated)
    xr_c = xr_n; xz_c = xz_n; xn_c = xn_n; dn_c = dn_n;
  }

  if (kk == NWIN-1){
    #pragma unroll
    for (int r2=0;r2<4;r2++)
      h_last[(size_t)(bt*16+q*4+r2)*H_DIM + w*16 + l] = hv[r2];
  }
}

// ============ K6: act = relu(ys@W_act+b); alpha/beta = softplus(act@W+b)+1 ============
__global__ __launch_bounds__(256) void k_heads(const short* __restrict__ yspk,
                                               const short* __restrict__ Bact,
                                               const float* __restrict__ b_act,
                                               const short* __restrict__ Bhead,
                                               const float* __restrict__ b_alpha,
                                               const float* __restrict__ b_beta,
                                               float* __restrict__ alpha,
                                               float* __restrict__ beta){
  int tid=threadIdx.x, w=tid>>6, lane=tid&63, q=lane>>4, l=lane&15;
  size_t rt = (size_t)blockIdx.x*4 + w;
  __shared__ __align__(16) short tl[4][16][136];
  const bf16x4* ys4 = (const bf16x4*)yspk;
  #pragma unroll
  for (int ct=0; ct<8; ct++){
    bf16x4 v = ys4[(rt*8+ct)*64+lane];
    #pragma unroll
    for (int r2=0;r2<4;r2++) tl[w][q*4+r2][ct*16+l] = v[r2];
  }
  __syncthreads();
  bf16x8 A[4];
  #pragma unroll
  for (int kb=0;kb<4;kb++) A[kb] = *(const bf16x8*)&tl[w][l][kb*32+q*8];
  __syncthreads();
  const bf16x8* BA = (const bf16x8*)Bact;
  f32x4 accA[8];
  #pragma unroll
  for (int ct=0;ct<8;ct++){ f32x4 z = {0.f,0.f,0.f,0.f}; accA[ct]=z; }
  #pragma unroll
  for (int ct=0;ct<8;ct++)
    #pragma unroll
    for (int kb=0;kb<4;kb++)
      accA[ct] = __builtin_amdgcn_mfma_f32_16x16x32_bf16(A[kb], BA[(ct*4+kb)*64+lane], accA[ct], 0,0,0);
  #pragma unroll
  for (int ct=0;ct<8;ct++){
    int col = ct*16 + l;
    float bb = b_act[col];
    #pragma unroll
    for (int r2=0;r2<4;r2++){
      float e = accA[ct][r2] + bb; e = e>0.f ? e : 0.f;
      tl[w][q*4+r2][col] = f2bf(e);
    }
  }
  __syncthreads();
  bf16x8 A2[4];
  #pragma unroll
  for (int kb=0;kb<4;kb++) A2[kb] = *(const bf16x8*)&tl[w][l][kb*32+q*8];
  const bf16x8* BHd = (const bf16x8*)Bhead;
  f32x4 acc = {0.f,0.f,0.f,0.f};
  #pragma unroll
  for (int kb=0;kb<4;kb++)
    acc = __builtin_amdgcn_mfma_f32_16x16x32_bf16(A2[kb], BHd[kb*64+lane], acc, 0,0,0);
  float bb = (l<8) ? b_alpha[l] : b_beta[l-8];
  float* dst = (l<8) ? alpha : beta;
  int cc = (l<8) ? l : l-8;
  #pragma unroll
  for (int r2=0;r2<4;r2++){
    float u = acc[r2] + bb;
    float sp = fmaxf(u,0.f) + log1pf(expf(-fabsf(u)));
    dst[(rt*16 + q*4 + r2)*8 + cc] = sp + 1.f;
  }
}

// ================= host launcher =================
extern "C" void kernel_launch(void* const* d_in, const int* in_sizes, int n_in,
                              void* d_out, int out_size, void* d_ws, size_t ws_size,
                              hipStream_t stream){
  const float* hidden   = (const float*)d_in[0];
  const float* obs      = (const float*)d_in[1];
  const unsigned char* dones = (const unsigned char*)d_in[2];
  const float* mean_obs = (const float*)d_in[3];
  const float* welfS    = (const float*)d_in[4];
  const int*   runcnt   = (const int*)d_in[5];
  const float* W_emb = (const float*)d_in[6];
  const float* b_emb = (const float*)d_in[7];
  const float* Wi    = (const float*)d_in[8];
  const float* Wh    = (const float*)d_in[9];
  const float* bh    = (const float*)d_in[10];
  const float* W_act = (const float*)d_in[11];
  const float* b_act = (const float*)d_in[12];
  const float* W_al  = (const float*)d_in[13];
  const float* b_al  = (const float*)d_in[14];
  const float* W_be  = (const float*)d_in[15];
  const float* b_be  = (const float*)d_in[16];
  float* out = (float*)d_out;
  char*  ws  = (char*)d_ws;

  double* psum = (double*)(ws + OFF_PSUM);
  double* psq  = (double*)(ws + OFF_PSQ);
  float*  wsM  = (float*)(ws + OFF_STATM);
  float*  wsI  = (float*)(ws + OFF_STATI);
  short*  Bemb = (short*)(ws + OFF_WEMB);
  short*  BWi  = (short*)(ws + OFF_WI);
  short*  BWh  = (short*)(ws + OFF_WH);
  short*  Bact = (short*)(ws + OFF_WACT);
  short*  Bhead= (short*)(ws + OFF_WHEAD);
  int*    tlo  = (int*)(ws + OFF_TLO);
  unsigned char* uh = (unsigned char*)(ws + OFF_UH);
  short*  xgpk = (short*)(ws + OFF_XG);
  short*  yspk = (short*)(ws + OFF_YS);

  k_partial<<<1024,256,0,stream>>>(obs, psum, psq);
  k_stats<<<1,1024,0,stream>>>(psum, psq, mean_obs, welfS, runcnt,
                               out+OUT_M, out+OUT_S, wsM, wsI);
  k_sched<<<8,512,0,stream>>>(dones, tlo, uh);
  k_pack_all<<<520,256,0,stream>>>(W_emb, Wi, Wh, W_act, W_al, W_be,
                                   Bemb, BWi, BWh, Bact, Bhead);
  k_embxg<<<8192,512,0,stream>>>(obs, wsM, wsI, Bemb, b_emb, BWi, xgpk);
  k_gru<<<256,512,0,stream>>>(hidden, dones, xgpk, BWh, bh, tlo, uh,
                              yspk, out + OUT_H);
  k_heads<<<2048,256,0,stream>>>(yspk, Bact, b_act, Bhead, b_al, b_be,
                                 out + OUT_ALPHA, out + OUT_BETA);
}

// Round 7
// 657.227 us; speedup vs baseline: 1.5604x; 1.0099x over previous
//
#include <hip/hip_runtime.h>

// ---------------- problem dims ----------------
#define T_DIM 256
#define B_DIM 512
#define D_DIM 128
#define H_DIM 128
#define A_DIM 8
#define N_ROWS (T_DIM*B_DIM)   // 131072 flattened rows
#define NT (N_ROWS/16)         // 8192 row tiles of 16
#define NWIN 8                 // time windows of 32 for the GRU

typedef __attribute__((ext_vector_type(4))) float f32x4;
typedef __attribute__((ext_vector_type(8))) short bf16x8;     // 8 bf16 in 4 VGPRs
typedef __attribute__((ext_vector_type(4))) short bf16x4;
typedef __attribute__((ext_vector_type(8))) _Float16 f16x8;   // 8 f16 in 4 VGPRs
typedef __attribute__((ext_vector_type(4))) unsigned u32x4;

// ---------------- workspace layout (bytes) ----------------
#define OFF_PSUM   0ull
#define OFF_PSQ    1048576ull
#define OFF_STATM  2097152ull
#define OFF_STATI  2097664ull
#define OFF_WEMB   2098176ull              // 16384 el bf16
#define OFF_WI     2130944ull              // 49152 el bf16
#define OFF_WH     2229248ull              // 49152 el f16
#define OFF_WACT   2425856ull              // 16384 el bf16
#define OFF_WHEAD  2458624ull              // 2048 el bf16
#define OFF_TLO    2462720ull              // 8*32 int
#define OFF_UH     2463744ull              // 8*512 bytes
#define OFF_XG     4194304ull              // 96 MB (C/D-frag order)
#define OFF_YS     104857600ull            // 32 MB (C/D-frag order)

// ---------------- output layout (f32 elements) ----------------
#define OUT_H      0
#define OUT_ALPHA  65536
#define OUT_BETA   1114112
#define OUT_M      2162688
#define OUT_S      2162816

__device__ inline short f2bf(float x){              // RNE f32->bf16
  union { float f; unsigned u; } v; v.f = x;
  unsigned r = v.u + 0x7FFFu + ((v.u>>16)&1u);
  return (short)(r>>16);
}
__device__ inline float bf2f(short h){
  union { unsigned u; float f; } v; v.u = ((unsigned)(unsigned short)h)<<16; return v.f;
}

// ============ K1: per-column partial sum / sumsq over obs rows ============
__global__ __launch_bounds__(256) void k_partial(const float* __restrict__ obs,
                                                 double* __restrict__ psum,
                                                 double* __restrict__ psq){
  int tid = threadIdx.x; int col = tid & 127; int rh = tid >> 7;
  double s = 0.0, q = 0.0;
  for (int r = blockIdx.x*2 + rh; r < N_ROWS; r += 2048){
    float v = obs[(size_t)r*D_DIM + col];
    s += (double)v; q += (double)v*(double)v;
  }
  __shared__ double ls[256], lq[256];
  ls[tid]=s; lq[tid]=q; __syncthreads();
  if (rh==0){
    psum[(size_t)blockIdx.x*128 + col] = ls[tid] + ls[tid+128];
    psq [(size_t)blockIdx.x*128 + col] = lq[tid] + lq[tid+128];
  }
}

// ============ K2: finalize Welford (chunk-combine) ============
__global__ __launch_bounds__(1024) void k_stats(const double* __restrict__ psum,
                                                const double* __restrict__ psq,
                                                const float* __restrict__ mean_obs,
                                                const float* __restrict__ welfS,
                                                const int* __restrict__ runcnt,
                                                float* __restrict__ outM, float* __restrict__ outS,
                                                float* __restrict__ wsM,  float* __restrict__ wsI){
  int tid = threadIdx.x; int col = tid & 127; int seg = tid >> 7;
  double s=0.0, q=0.0;
  for (int b=seg; b<1024; b+=8){ s += psum[(size_t)b*128+col]; q += psq[(size_t)b*128+col]; }
  __shared__ double ls[1024], lq[1024];
  ls[tid]=s; lq[tid]=q; __syncthreads();
  if (seg==0){
    for (int b=1;b<8;b++){ s += ls[b*128+col]; q += lq[b*128+col]; }
    double c0 = (double)runcnt[0];
    double Nn = (double)N_ROWS;
    double n  = c0 + Nn;
    double M0 = (double)mean_obs[col], S0 = (double)welfS[col];
    double mb = s / Nn;
    double delta = mb - M0;
    double M = M0 + delta * Nn / n;
    double M2b = q - Nn*mb*mb;
    double S = S0 + M2b + delta*delta*c0*Nn/n;
    double var = S / (n - 1.0);
    float inv = (float)(1.0/(sqrt(var)+1e-8));
    outM[col] = (float)M; outS[col] = (float)S;
    wsM[col]  = (float)M; wsI[col]  = inv;
  }
}

// ============ K3: all weight packs in ONE launch ============
// frag layout: ((ct*4+kb)*64+lane)*8+j holds W[k=kb*32+(lane>>4)*8+j][n=ct*16+(lane&15)]
__global__ void k_pack_all(const float* __restrict__ W_emb, const float* __restrict__ Wi,
                           const float* __restrict__ Wh,    const float* __restrict__ W_act,
                           const float* __restrict__ W_al,  const float* __restrict__ W_be,
                           short* __restrict__ Bemb, short* __restrict__ BWi,
                           short* __restrict__ BWh,  short* __restrict__ Bact,
                           short* __restrict__ Bhead){
  int gidx = blockIdx.x*256 + threadIdx.x;
  if (gidx >= 133120) return;
  if (gidx >= 131072){
    int idx = gidx - 131072;
    int j = idx & 7, lane = (idx>>3)&63, kb = (idx>>9)&3;
    int k = kb*32 + (lane>>4)*8 + j;
    int n = lane & 15;
    float wv = (n<8) ? W_al[(size_t)k*8 + n] : W_be[(size_t)k*8 + (n-8)];
    Bhead[idx] = f2bf(wv);
    return;
  }
  const float* src; short* dst; int C; int fmt; int idx;   // fmt 0=bf16 1=f16
  if (gidx < 16384)      { src=W_emb; dst=Bemb; C=128; fmt=0; idx=gidx; }
  else if (gidx < 65536) { src=Wi;    dst=BWi;  C=384; fmt=0; idx=gidx-16384; }
  else if (gidx < 114688){ src=Wh;    dst=BWh;  C=384; fmt=1; idx=gidx-65536; }
  else                   { src=W_act; dst=Bact; C=128; fmt=0; idx=gidx-114688; }
  int j = idx & 7, lane = (idx>>3)&63, kb = (idx>>9)&3, ct = idx>>11;
  int k = kb*32 + (lane>>4)*8 + j;
  int n = ct*16 + (lane&15);
  float wv = src[(size_t)k*C + n];
  short h;
  if (fmt==0) h = f2bf(wv);
  else { union { _Float16 hf; short s; } u; u.hf = (_Float16)wv; h = u.s; }
  dst[idx] = h;
}

// ============ K3b: window schedule ============
__global__ __launch_bounds__(512) void k_sched(const unsigned char* __restrict__ dones,
                                               int* __restrict__ tlo,
                                               unsigned char* __restrict__ usehid){
  int k = blockIdx.x;         // 0..7
  int b = threadIdx.x;        // 0..511
  int t0 = 0, uh = 1;
  if (k > 0){
    for (int t = 32*k; t >= 0; t--){
      if (dones[(size_t)t*B_DIM + b]){ t0 = t; uh = 0; break; }
    }
  }
  usehid[k*B_DIM + b] = (unsigned char)uh;
  __shared__ int red[512];
  red[b] = t0; __syncthreads();
  if (b < 32){
    int m = red[b*16];
    #pragma unroll
    for (int i=1;i<16;i++) m = min(m, red[b*16+i]);
    tlo[k*32 + b] = m;
  }
}

// ============ K4: fused normalize -> emb(MFMA) -> relu -> xg(MFMA) ============
__global__ __launch_bounds__(512) void k_embxg(const float* __restrict__ obs,
                                               const float* __restrict__ wsM,
                                               const float* __restrict__ wsI,
                                               const short* __restrict__ Bemb,
                                               const float* __restrict__ b_emb,
                                               const short* __restrict__ BWi,
                                               short* __restrict__ xgpk){
  int tid=threadIdx.x, w=tid>>6, lane=tid&63, q=lane>>4, l=lane&15;
  int rt = blockIdx.x;
  int r0 = rt*16;
  __shared__ __align__(16) short obsL[16][136];
  __shared__ __align__(16) short embL[16][136];

  {
    int row = tid>>5, seg = tid&31;
    f32x4 o = *(const f32x4*)(obs + (size_t)(r0+row)*D_DIM + seg*4);
    f32x4 m = *(const f32x4*)(wsM + seg*4);
    f32x4 iv= *(const f32x4*)(wsI + seg*4);
    bf16x4 v;
    v[0]=f2bf((o[0]-m[0])*iv[0]); v[1]=f2bf((o[1]-m[1])*iv[1]);
    v[2]=f2bf((o[2]-m[2])*iv[2]); v[3]=f2bf((o[3]-m[3])*iv[3]);
    *(bf16x4*)&obsL[row][seg*4] = v;
  }
  __syncthreads();

  bf16x8 A[4];
  #pragma unroll
  for (int kb=0;kb<4;kb++) A[kb] = *(const bf16x8*)&obsL[l][kb*32+q*8];

  const bf16x8* BE = (const bf16x8*)Bemb;
  f32x4 accE = {0.f,0.f,0.f,0.f};
  #pragma unroll
  for (int kb=0;kb<4;kb++)
    accE = __builtin_amdgcn_mfma_f32_16x16x32_bf16(A[kb], BE[(w*4+kb)*64+lane], accE, 0,0,0);
  {
    float bb = b_emb[w*16 + l];
    #pragma unroll
    for (int r2=0;r2<4;r2++){
      float e = accE[r2] + bb; e = e>0.f ? e : 0.f;
      embL[q*4+r2][w*16+l] = f2bf(e);
    }
  }
  __syncthreads();

  bf16x8 A2[4];
  #pragma unroll
  for (int kb=0;kb<4;kb++) A2[kb] = *(const bf16x8*)&embL[l][kb*32+q*8];

  const bf16x8* BW = (const bf16x8*)BWi;
  bf16x4* xg4 = (bf16x4*)xgpk;
  #pragma unroll
  for (int g=0; g<3; g++){
    int ct = g*8 + w;
    f32x4 acc = {0.f,0.f,0.f,0.f};
    #pragma unroll
    for (int kb=0;kb<4;kb++)
      acc = __builtin_amdgcn_mfma_f32_16x16x32_bf16(A2[kb], BW[(ct*4+kb)*64+lane], acc, 0,0,0);
    bf16x4 v;
    v[0]=f2bf(acc[0]); v[1]=f2bf(acc[1]); v[2]=f2bf(acc[2]); v[3]=f2bf(acc[3]);
    xg4[((size_t)rt*24 + ct)*64 + lane] = v;
  }
}

// ============ K5: window-parallel GRU — volatile-pinned register B ============
// 12 MFMA/iter. B-frags loaded ONCE via volatile (non-rematerializable,
// non-duplicable) into 12 individually-named f16x8 SSA values -> must stay
// register-resident (~120 VGPR total, 1 block/CU). Plain __syncthreads, no asm.
#define LDB(g,kb) __builtin_bit_cast(f16x8, pvw[(((g)*8+w)*4+(kb))*64+lane])
__global__ __launch_bounds__(512,1) void k_gru(const float* __restrict__ hidden,
                                             const unsigned char* __restrict__ dones,
                                             const short* __restrict__ xgpk,
                                             const short* __restrict__ BWh,
                                             const float* __restrict__ bh,
                                             const int* __restrict__ tlo,
                                             const unsigned char* __restrict__ usehid,
                                             short* __restrict__ yspk,
                                             float* __restrict__ h_last){
  int tid=threadIdx.x, w=tid>>6, lane=tid&63, q=lane>>4, l=lane&15;
  int kk = blockIdx.x >> 5, bt = blockIdx.x & 31;
  int t_out0 = kk*32;
  int t_end  = t_out0 + 32;
  int t_start = tlo[kk*32 + bt];

  __shared__ __align__(16) _Float16 hF[2][16][136];   // 8704 B

  // 12 B-fragments, volatile-loaded once, individually named (no arrays).
  const volatile u32x4* pvw = (const volatile u32x4*)BWh;
  f16x8 B00 = LDB(0,0), B01 = LDB(0,1), B02 = LDB(0,2), B03 = LDB(0,3);
  f16x8 B10 = LDB(1,0), B11 = LDB(1,1), B12 = LDB(1,2), B13 = LDB(1,3);
  f16x8 B20 = LDB(2,0), B21 = LDB(2,1), B22 = LDB(2,2), B23 = LDB(2,3);

  float bh0 = bh[0*128 + w*16 + l];
  float bh1 = bh[1*128 + w*16 + l];
  float bh2 = bh[2*128 + w*16 + l];

  float hv[4];
  #pragma unroll
  for (int r2=0;r2<4;r2++){
    int b = bt*16 + q*4 + r2;
    hv[r2] = usehid[kk*B_DIM + b] ? hidden[(size_t)b*H_DIM + w*16 + l] : 0.f;
  }

  // running pointers (uniform per-iter strides)
  const bf16x4* xgt = (const bf16x4*)xgpk + (((size_t)t_start*32 + bt)*24 + w)*64 + lane;
  const unsigned char* dnp = dones + (size_t)t_start*B_DIM + bt*16 + q*4;
  bf16x4* yst = (bf16x4*)yspk + (((size_t)t_start*32 + bt)*8 + w)*64 + lane;

  bf16x4 xr_c = xgt[0], xz_c = xgt[512], xn_c = xgt[1024];   // gate stride 8*64
  unsigned dn_c = *(const unsigned*)dnp;

  for (int t = t_start; t < t_end; t++){
    int buf = t & 1;
    #pragma unroll
    for (int r2=0;r2<4;r2++){
      float hvv = ((dn_c >> (r2*8)) & 255u) ? 0.f : hv[r2];
      hv[r2] = hvv;
      hF[buf][q*4+r2][w*16+l] = (_Float16)hvv;
    }
    __syncthreads();

    // advance + prefetch step t+1 (advance 0 on last iter -> no OOB)
    int adv = (t+1 < t_end) ? 1 : 0;
    xgt += (size_t)adv * 49152;       // 32 tiles * 24 * 64
    dnp += adv * B_DIM;
    bf16x4 xr_n = xgt[0], xz_n = xgt[512], xn_n = xgt[1024];
    unsigned dn_n = *(const unsigned*)dnp;

    f16x8 A0 = *(const f16x8*)&hF[buf][l][0*32+q*8];
    f16x8 A1 = *(const f16x8*)&hF[buf][l][1*32+q*8];
    f16x8 A2 = *(const f16x8*)&hF[buf][l][2*32+q*8];
    f16x8 A3 = *(const f16x8*)&hF[buf][l][3*32+q*8];

    f32x4 acc0 = {0.f,0.f,0.f,0.f}, acc1 = {0.f,0.f,0.f,0.f}, acc2 = {0.f,0.f,0.f,0.f};
    acc0 = __builtin_amdgcn_mfma_f32_16x16x32_f16(A0, B00, acc0, 0,0,0);
    acc1 = __builtin_amdgcn_mfma_f32_16x16x32_f16(A0, B10, acc1, 0,0,0);
    acc2 = __builtin_amdgcn_mfma_f32_16x16x32_f16(A0, B20, acc2, 0,0,0);
    acc0 = __builtin_amdgcn_mfma_f32_16x16x32_f16(A1, B01, acc0, 0,0,0);
    acc1 = __builtin_amdgcn_mfma_f32_16x16x32_f16(A1, B11, acc1, 0,0,0);
    acc2 = __builtin_amdgcn_mfma_f32_16x16x32_f16(A1, B21, acc2, 0,0,0);
    acc0 = __builtin_amdgcn_mfma_f32_16x16x32_f16(A2, B02, acc0, 0,0,0);
    acc1 = __builtin_amdgcn_mfma_f32_16x16x32_f16(A2, B12, acc1, 0,0,0);
    acc2 = __builtin_amdgcn_mfma_f32_16x16x32_f16(A2, B22, acc2, 0,0,0);
    acc0 = __builtin_amdgcn_mfma_f32_16x16x32_f16(A3, B03, acc0, 0,0,0);
    acc1 = __builtin_amdgcn_mfma_f32_16x16x32_f16(A3, B13, acc1, 0,0,0);
    acc2 = __builtin_amdgcn_mfma_f32_16x16x32_f16(A3, B23, acc2, 0,0,0);

    #pragma unroll
    for (int r2=0;r2<4;r2++){
      float xr = bf2f(xr_c[r2]), xz = bf2f(xz_c[r2]), xn = bf2f(xn_c[r2]);
      float rg = 1.f/(1.f + __expf(-(xr + acc0[r2] + bh0)));
      float zg = 1.f/(1.f + __expf(-(xz + acc1[r2] + bh1)));
      float nu = xn + rg*(acc2[r2] + bh2);
      float e2 = __expf(2.f*nu);
      float ng = 1.f - 2.f/(e2 + 1.f);          // tanh, inf-safe
      hv[r2] = (1.f - zg)*ng + zg*hv[r2];
    }
    if (t >= t_out0){
      bf16x4 yv;
      yv[0]=f2bf(hv[0]); yv[1]=f2bf(hv[1]); yv[2]=f2bf(hv[2]); yv[3]=f2bf(hv[3]);
      *yst = yv;
    }
    yst += 16384;                     // 32 tiles * 8 * 64 (advance always; deref gated)
    xr_c = xr_n; xz_c = xz_n; xn_c = xn_n; dn_c = dn_n;
  }

  if (kk == NWIN-1){
    #pragma unroll
    for (int r2=0;r2<4;r2++)
      h_last[(size_t)(bt*16+q*4+r2)*H_DIM + w*16 + l] = hv[r2];
  }
}

// ============ K6: act = relu(ys@W_act+b); alpha/beta = softplus(act@W+b)+1 ============
__global__ __launch_bounds__(256) void k_heads(const short* __restrict__ yspk,
                                               const short* __restrict__ Bact,
                                               const float* __restrict__ b_act,
                                               const short* __restrict__ Bhead,
                                               const float* __restrict__ b_alpha,
                                               const float* __restrict__ b_beta,
                                               float* __restrict__ alpha,
                                               float* __restrict__ beta){
  int tid=threadIdx.x, w=tid>>6, lane=tid&63, q=lane>>4, l=lane&15;
  size_t rt = (size_t)blockIdx.x*4 + w;
  __shared__ __align__(16) short tl[4][16][136];
  const bf16x4* ys4 = (const bf16x4*)yspk;
  #pragma unroll
  for (int ct=0; ct<8; ct++){
    bf16x4 v = ys4[(rt*8+ct)*64+lane];
    #pragma unroll
    for (int r2=0;r2<4;r2++) tl[w][q*4+r2][ct*16+l] = v[r2];
  }
  __syncthreads();
  bf16x8 A[4];
  #pragma unroll
  for (int kb=0;kb<4;kb++) A[kb] = *(const bf16x8*)&tl[w][l][kb*32+q*8];
  __syncthreads();
  const bf16x8* BA = (const bf16x8*)Bact;
  f32x4 accA[8];
  #pragma unroll
  for (int ct=0;ct<8;ct++){ f32x4 z = {0.f,0.f,0.f,0.f}; accA[ct]=z; }
  #pragma unroll
  for (int ct=0;ct<8;ct++)
    #pragma unroll
    for (int kb=0;kb<4;kb++)
      accA[ct] = __builtin_amdgcn_mfma_f32_16x16x32_bf16(A[kb], BA[(ct*4+kb)*64+lane], accA[ct], 0,0,0);
  #pragma unroll
  for (int ct=0;ct<8;ct++){
    int col = ct*16 + l;
    float bb = b_act[col];
    #pragma unroll
    for (int r2=0;r2<4;r2++){
      float e = accA[ct][r2] + bb; e = e>0.f ? e : 0.f;
      tl[w][q*4+r2][col] = f2bf(e);
    }
  }
  __syncthreads();
  bf16x8 A2[4];
  #pragma unroll
  for (int kb=0;kb<4;kb++) A2[kb] = *(const bf16x8*)&tl[w][l][kb*32+q*8];
  const bf16x8* BHd = (const bf16x8*)Bhead;
  f32x4 acc = {0.f,0.f,0.f,0.f};
  #pragma unroll
  for (int kb=0;kb<4;kb++)
    acc = __builtin_amdgcn_mfma_f32_16x16x32_bf16(A2[kb], BHd[kb*64+lane], acc, 0,0,0);
  float bb = (l<8) ? b_alpha[l] : b_beta[l-8];
  float* dst = (l<8) ? alpha : beta;
  int cc = (l<8) ? l : l-8;
  #pragma unroll
  for (int r2=0;r2<4;r2++){
    float u = acc[r2] + bb;
    float sp = fmaxf(u,0.f) + log1pf(expf(-fabsf(u)));
    dst[(rt*16 + q*4 + r2)*8 + cc] = sp + 1.f;
  }
}

// ================= host launcher =================
extern "C" void kernel_launch(void* const* d_in, const int* in_sizes, int n_in,
                              void* d_out, int out_size, void* d_ws, size_t ws_size,
                              hipStream_t stream){
  const float* hidden   = (const float*)d_in[0];
  const float* obs      = (const float*)d_in[1];
  const unsigned char* dones = (const unsigned char*)d_in[2];
  const float* mean_obs = (const float*)d_in[3];
  const float* welfS    = (const float*)d_in[4];
  const int*   runcnt   = (const int*)d_in[5];
  const float* W_emb = (const float*)d_in[6];
  const float* b_emb = (const float*)d_in[7];
  const float* Wi    = (const float*)d_in[8];
  const float* Wh    = (const float*)d_in[9];
  const float* bh    = (const float*)d_in[10];
  const float* W_act = (const float*)d_in[11];
  const float* b_act = (const float*)d_in[12];
  const float* W_al  = (const float*)d_in[13];
  const float* b_al  = (const float*)d_in[14];
  const float* W_be  = (const float*)d_in[15];
  const float* b_be  = (const float*)d_in[16];
  float* out = (float*)d_out;
  char*  ws  = (char*)d_ws;

  double* psum = (double*)(ws + OFF_PSUM);
  double* psq  = (double*)(ws + OFF_PSQ);
  float*  wsM  = (float*)(ws + OFF_STATM);
  float*  wsI  = (float*)(ws + OFF_STATI);
  short*  Bemb = (short*)(ws + OFF_WEMB);
  short*  BWi  = (short*)(ws + OFF_WI);
  short*  BWh  = (short*)(ws + OFF_WH);
  short*  Bact = (short*)(ws + OFF_WACT);
  short*  Bhead= (short*)(ws + OFF_WHEAD);
  int*    tlo  = (int*)(ws + OFF_TLO);
  unsigned char* uh = (unsigned char*)(ws + OFF_UH);
  short*  xgpk = (short*)(ws + OFF_XG);
  short*  yspk = (short*)(ws + OFF_YS);

  k_partial<<<1024,256,0,stream>>>(obs, psum, psq);
  k_stats<<<1,1024,0,stream>>>(psum, psq, mean_obs, welfS, runcnt,
                               out+OUT_M, out+OUT_S, wsM, wsI);
  k_sched<<<8,512,0,stream>>>(dones, tlo, uh);
  k_pack_all<<<520,256,0,stream>>>(W_emb, Wi, Wh, W_act, W_al, W_be,
                                   Bemb, BWi, BWh, Bact, Bhead);
  k_embxg<<<8192,512,0,stream>>>(obs, wsM, wsI, Bemb, b_emb, BWi, xgpk);
  k_gru<<<256,512,0,stream>>>(hidden, dones, xgpk, BWh, bh, tlo, uh,
                              yspk, out + OUT_H);
  k_heads<<<2048,256,0,stream>>>(yspk, Bact, b_act, Bhead, b_al, b_be,
                                 out + OUT_ALPHA, out + OUT_BETA);
}

// Round 8
// 626.454 us; speedup vs baseline: 1.6371x; 1.0491x over previous
//
#include <hip/hip_runtime.h>

// ---------------- problem dims ----------------
#define T_DIM 256
#define B_DIM 512
#define D_DIM 128
#define H_DIM 128
#define A_DIM 8
#define N_ROWS (T_DIM*B_DIM)   // 131072 flattened rows
#define NT (N_ROWS/16)         // 8192 row tiles of 16
#define NWIN 8                 // time windows of 32 for the GRU

typedef __attribute__((ext_vector_type(4))) float f32x4;
typedef __attribute__((ext_vector_type(8))) short bf16x8;     // 8 bf16 in 4 VGPRs
typedef __attribute__((ext_vector_type(4))) short bf16x4;
typedef __attribute__((ext_vector_type(8))) _Float16 f16x8;   // 8 f16 in 4 VGPRs
typedef __attribute__((ext_vector_type(4))) unsigned u32x4;

// ---------------- workspace layout (bytes) ----------------
#define OFF_PSUM   0ull
#define OFF_PSQ    1048576ull
#define OFF_STATM  2097152ull
#define OFF_STATI  2097664ull
#define OFF_WEMB   2098176ull              // 16384 el bf16
#define OFF_WI     2130944ull              // 49152 el bf16
#define OFF_WH     2229248ull              // 49152 el f16
#define OFF_WACT   2425856ull              // 16384 el bf16
#define OFF_WHEAD  2458624ull              // 2048 el bf16
#define OFF_TLO    2462720ull              // 8*32 int
#define OFF_UH     2463744ull              // 8*512 bytes
#define OFF_XG     4194304ull              // 96 MB (C/D-frag order)
#define OFF_YS     104857600ull            // 32 MB (C/D-frag order)

// ---------------- output layout (f32 elements) ----------------
#define OUT_H      0
#define OUT_ALPHA  65536
#define OUT_BETA   1114112
#define OUT_M      2162688
#define OUT_S      2162816

__device__ inline short f2bf(float x){              // RNE f32->bf16
  union { float f; unsigned u; } v; v.f = x;
  unsigned r = v.u + 0x7FFFu + ((v.u>>16)&1u);
  return (short)(r>>16);
}
__device__ inline float bf2f(short h){
  union { unsigned u; float f; } v; v.u = ((unsigned)(unsigned short)h)<<16; return v.f;
}

// ============ K1: per-column partial sum / sumsq over obs rows ============
__global__ __launch_bounds__(256) void k_partial(const float* __restrict__ obs,
                                                 double* __restrict__ psum,
                                                 double* __restrict__ psq){
  int tid = threadIdx.x; int col = tid & 127; int rh = tid >> 7;
  double s = 0.0, q = 0.0;
  for (int r = blockIdx.x*2 + rh; r < N_ROWS; r += 2048){
    float v = obs[(size_t)r*D_DIM + col];
    s += (double)v; q += (double)v*(double)v;
  }
  __shared__ double ls[256], lq[256];
  ls[tid]=s; lq[tid]=q; __syncthreads();
  if (rh==0){
    psum[(size_t)blockIdx.x*128 + col] = ls[tid] + ls[tid+128];
    psq [(size_t)blockIdx.x*128 + col] = lq[tid] + lq[tid+128];
  }
}

// ============ K2: finalize Welford (chunk-combine) ============
__global__ __launch_bounds__(1024) void k_stats(const double* __restrict__ psum,
                                                const double* __restrict__ psq,
                                                const float* __restrict__ mean_obs,
                                                const float* __restrict__ welfS,
                                                const int* __restrict__ runcnt,
                                                float* __restrict__ outM, float* __restrict__ outS,
                                                float* __restrict__ wsM,  float* __restrict__ wsI){
  int tid = threadIdx.x; int col = tid & 127; int seg = tid >> 7;
  double s=0.0, q=0.0;
  for (int b=seg; b<1024; b+=8){ s += psum[(size_t)b*128+col]; q += psq[(size_t)b*128+col]; }
  __shared__ double ls[1024], lq[1024];
  ls[tid]=s; lq[tid]=q; __syncthreads();
  if (seg==0){
    for (int b=1;b<8;b++){ s += ls[b*128+col]; q += lq[b*128+col]; }
    double c0 = (double)runcnt[0];
    double Nn = (double)N_ROWS;
    double n  = c0 + Nn;
    double M0 = (double)mean_obs[col], S0 = (double)welfS[col];
    double mb = s / Nn;
    double delta = mb - M0;
    double M = M0 + delta * Nn / n;
    double M2b = q - Nn*mb*mb;
    double S = S0 + M2b + delta*delta*c0*Nn/n;
    double var = S / (n - 1.0);
    float inv = (float)(1.0/(sqrt(var)+1e-8));
    outM[col] = (float)M; outS[col] = (float)S;
    wsM[col]  = (float)M; wsI[col]  = inv;
  }
}

// ============ K3: all weight packs in ONE launch ============
// frag layout: ((ct*4+kb)*64+lane)*8+j holds W[k=kb*32+(lane>>4)*8+j][n=ct*16+(lane&15)]
__global__ void k_pack_all(const float* __restrict__ W_emb, const float* __restrict__ Wi,
                           const float* __restrict__ Wh,    const float* __restrict__ W_act,
                           const float* __restrict__ W_al,  const float* __restrict__ W_be,
                           short* __restrict__ Bemb, short* __restrict__ BWi,
                           short* __restrict__ BWh,  short* __restrict__ Bact,
                           short* __restrict__ Bhead){
  int gidx = blockIdx.x*256 + threadIdx.x;
  if (gidx >= 133120) return;
  if (gidx >= 131072){
    int idx = gidx - 131072;
    int j = idx & 7, lane = (idx>>3)&63, kb = (idx>>9)&3;
    int k = kb*32 + (lane>>4)*8 + j;
    int n = lane & 15;
    float wv = (n<8) ? W_al[(size_t)k*8 + n] : W_be[(size_t)k*8 + (n-8)];
    Bhead[idx] = f2bf(wv);
    return;
  }
  const float* src; short* dst; int C; int fmt; int idx;   // fmt 0=bf16 1=f16
  if (gidx < 16384)      { src=W_emb; dst=Bemb; C=128; fmt=0; idx=gidx; }
  else if (gidx < 65536) { src=Wi;    dst=BWi;  C=384; fmt=0; idx=gidx-16384; }
  else if (gidx < 114688){ src=Wh;    dst=BWh;  C=384; fmt=1; idx=gidx-65536; }
  else                   { src=W_act; dst=Bact; C=128; fmt=0; idx=gidx-114688; }
  int j = idx & 7, lane = (idx>>3)&63, kb = (idx>>9)&3, ct = idx>>11;
  int k = kb*32 + (lane>>4)*8 + j;
  int n = ct*16 + (lane&15);
  float wv = src[(size_t)k*C + n];
  short h;
  if (fmt==0) h = f2bf(wv);
  else { union { _Float16 hf; short s; } u; u.hf = (_Float16)wv; h = u.s; }
  dst[idx] = h;
}

// ============ K3b: window schedule ============
__global__ __launch_bounds__(512) void k_sched(const unsigned char* __restrict__ dones,
                                               int* __restrict__ tlo,
                                               unsigned char* __restrict__ usehid){
  int k = blockIdx.x;         // 0..7
  int b = threadIdx.x;        // 0..511
  int t0 = 0, uh = 1;
  if (k > 0){
    for (int t = 32*k; t >= 0; t--){
      if (dones[(size_t)t*B_DIM + b]){ t0 = t; uh = 0; break; }
    }
  }
  usehid[k*B_DIM + b] = (unsigned char)uh;
  __shared__ int red[512];
  red[b] = t0; __syncthreads();
  if (b < 32){
    int m = red[b*16];
    #pragma unroll
    for (int i=1;i<16;i++) m = min(m, red[b*16+i]);
    tlo[k*32 + b] = m;
  }
}

// ============ K4: fused normalize -> emb(MFMA) -> relu -> xg(MFMA) ============
__global__ __launch_bounds__(512) void k_embxg(const float* __restrict__ obs,
                                               const float* __restrict__ wsM,
                                               const float* __restrict__ wsI,
                                               const short* __restrict__ Bemb,
                                               const float* __restrict__ b_emb,
                                               const short* __restrict__ BWi,
                                               short* __restrict__ xgpk){
  int tid=threadIdx.x, w=tid>>6, lane=tid&63, q=lane>>4, l=lane&15;
  int rt = blockIdx.x;
  int r0 = rt*16;
  __shared__ __align__(16) short obsL[16][136];
  __shared__ __align__(16) short embL[16][136];

  {
    int row = tid>>5, seg = tid&31;
    f32x4 o = *(const f32x4*)(obs + (size_t)(r0+row)*D_DIM + seg*4);
    f32x4 m = *(const f32x4*)(wsM + seg*4);
    f32x4 iv= *(const f32x4*)(wsI + seg*4);
    bf16x4 v;
    v[0]=f2bf((o[0]-m[0])*iv[0]); v[1]=f2bf((o[1]-m[1])*iv[1]);
    v[2]=f2bf((o[2]-m[2])*iv[2]); v[3]=f2bf((o[3]-m[3])*iv[3]);
    *(bf16x4*)&obsL[row][seg*4] = v;
  }
  __syncthreads();

  bf16x8 A[4];
  #pragma unroll
  for (int kb=0;kb<4;kb++) A[kb] = *(const bf16x8*)&obsL[l][kb*32+q*8];

  const bf16x8* BE = (const bf16x8*)Bemb;
  f32x4 accE = {0.f,0.f,0.f,0.f};
  #pragma unroll
  for (int kb=0;kb<4;kb++)
    accE = __builtin_amdgcn_mfma_f32_16x16x32_bf16(A[kb], BE[(w*4+kb)*64+lane], accE, 0,0,0);
  {
    float bb = b_emb[w*16 + l];
    #pragma unroll
    for (int r2=0;r2<4;r2++){
      float e = accE[r2] + bb; e = e>0.f ? e : 0.f;
      embL[q*4+r2][w*16+l] = f2bf(e);
    }
  }
  __syncthreads();

  bf16x8 A2[4];
  #pragma unroll
  for (int kb=0;kb<4;kb++) A2[kb] = *(const bf16x8*)&embL[l][kb*32+q*8];

  const bf16x8* BW = (const bf16x8*)BWi;
  bf16x4* xg4 = (bf16x4*)xgpk;
  #pragma unroll
  for (int g=0; g<3; g++){
    int ct = g*8 + w;
    f32x4 acc = {0.f,0.f,0.f,0.f};
    #pragma unroll
    for (int kb=0;kb<4;kb++)
      acc = __builtin_amdgcn_mfma_f32_16x16x32_bf16(A2[kb], BW[(ct*4+kb)*64+lane], acc, 0,0,0);
    bf16x4 v;
    v[0]=f2bf(acc[0]); v[1]=f2bf(acc[1]); v[2]=f2bf(acc[2]); v[3]=f2bf(acc[3]);
    xg4[((size_t)rt*24 + ct)*64 + lane] = v;
  }
}

// ============ K5: window-parallel GRU — occupancy-clamped register B ============
// ROOT-CAUSE FIX: amdgpu_waves_per_eu(2,2) clamps the backend's occupancy
// target to the structural 2 waves/EU of a 512-thread block, raising the
// VGPR budget to 256/wave so the 12 B-frags (48 VGPRs) + state stay
// register-resident instead of being spilled/reloaded every iteration
// (R3-R7: ~750 compiler-generated spill insts/iter at VGPR_Count=52).
#define LDB(g,kb) __builtin_bit_cast(f16x8, pw4[(((g)*8+w)*4+(kb))*64+lane])
__global__
__attribute__((amdgpu_flat_work_group_size(512,512)))
__attribute__((amdgpu_waves_per_eu(2,2)))
void k_gru(const float* __restrict__ hidden,
           const unsigned char* __restrict__ dones,
           const short* __restrict__ xgpk,
           const short* __restrict__ BWh,
           const float* __restrict__ bh,
           const int* __restrict__ tlo,
           const unsigned char* __restrict__ usehid,
           short* __restrict__ yspk,
           float* __restrict__ h_last){
  int tid=threadIdx.x, w=tid>>6, lane=tid&63, q=lane>>4, l=lane&15;
  int kk = blockIdx.x >> 5, bt = blockIdx.x & 31;
  int t_out0 = kk*32;
  int t_end  = t_out0 + 32;
  int t_start = tlo[kk*32 + bt];

  __shared__ __align__(16) _Float16 hF[2][16][136];   // 8704 B

  // 12 B-fragments, loaded once, individually named SSA values.
  const u32x4* pw4 = (const u32x4*)BWh;
  f16x8 B00 = LDB(0,0), B01 = LDB(0,1), B02 = LDB(0,2), B03 = LDB(0,3);
  f16x8 B10 = LDB(1,0), B11 = LDB(1,1), B12 = LDB(1,2), B13 = LDB(1,3);
  f16x8 B20 = LDB(2,0), B21 = LDB(2,1), B22 = LDB(2,2), B23 = LDB(2,3);

  float bh0 = bh[0*128 + w*16 + l];
  float bh1 = bh[1*128 + w*16 + l];
  float bh2 = bh[2*128 + w*16 + l];

  float hv[4];
  #pragma unroll
  for (int r2=0;r2<4;r2++){
    int b = bt*16 + q*4 + r2;
    hv[r2] = usehid[kk*B_DIM + b] ? hidden[(size_t)b*H_DIM + w*16 + l] : 0.f;
  }

  // running pointers (uniform per-iter strides)
  const bf16x4* xgt = (const bf16x4*)xgpk + (((size_t)t_start*32 + bt)*24 + w)*64 + lane;
  const unsigned char* dnp = dones + (size_t)t_start*B_DIM + bt*16 + q*4;
  bf16x4* yst = (bf16x4*)yspk + (((size_t)t_start*32 + bt)*8 + w)*64 + lane;

  bf16x4 xr_c = xgt[0], xz_c = xgt[512], xn_c = xgt[1024];   // gate stride 8*64
  unsigned dn_c = *(const unsigned*)dnp;

  for (int t = t_start; t < t_end; t++){
    int buf = t & 1;
    #pragma unroll
    for (int r2=0;r2<4;r2++){
      float hvv = ((dn_c >> (r2*8)) & 255u) ? 0.f : hv[r2];
      hv[r2] = hvv;
      hF[buf][q*4+r2][w*16+l] = (_Float16)hvv;
    }
    __syncthreads();

    // advance + prefetch step t+1 (advance 0 on last iter -> no OOB)
    int adv = (t+1 < t_end) ? 1 : 0;
    xgt += (size_t)adv * 49152;       // 32 tiles * 24 * 64
    dnp += adv * B_DIM;
    bf16x4 xr_n = xgt[0], xz_n = xgt[512], xn_n = xgt[1024];
    unsigned dn_n = *(const unsigned*)dnp;

    f16x8 A0 = *(const f16x8*)&hF[buf][l][0*32+q*8];
    f16x8 A1 = *(const f16x8*)&hF[buf][l][1*32+q*8];
    f16x8 A2 = *(const f16x8*)&hF[buf][l][2*32+q*8];
    f16x8 A3 = *(const f16x8*)&hF[buf][l][3*32+q*8];

    f32x4 acc0 = {0.f,0.f,0.f,0.f}, acc1 = {0.f,0.f,0.f,0.f}, acc2 = {0.f,0.f,0.f,0.f};
    acc0 = __builtin_amdgcn_mfma_f32_16x16x32_f16(A0, B00, acc0, 0,0,0);
    acc1 = __builtin_amdgcn_mfma_f32_16x16x32_f16(A0, B10, acc1, 0,0,0);
    acc2 = __builtin_amdgcn_mfma_f32_16x16x32_f16(A0, B20, acc2, 0,0,0);
    acc0 = __builtin_amdgcn_mfma_f32_16x16x32_f16(A1, B01, acc0, 0,0,0);
    acc1 = __builtin_amdgcn_mfma_f32_16x16x32_f16(A1, B11, acc1, 0,0,0);
    acc2 = __builtin_amdgcn_mfma_f32_16x16x32_f16(A1, B21, acc2, 0,0,0);
    acc0 = __builtin_amdgcn_mfma_f32_16x16x32_f16(A2, B02, acc0, 0,0,0);
    acc1 = __builtin_amdgcn_mfma_f32_16x16x32_f16(A2, B12, acc1, 0,0,0);
    acc2 = __builtin_amdgcn_mfma_f32_16x16x32_f16(A2, B22, acc2, 0,0,0);
    acc0 = __builtin_amdgcn_mfma_f32_16x16x32_f16(A3, B03, acc0, 0,0,0);
    acc1 = __builtin_amdgcn_mfma_f32_16x16x32_f16(A3, B13, acc1, 0,0,0);
    acc2 = __builtin_amdgcn_mfma_f32_16x16x32_f16(A3, B23, acc2, 0,0,0);

    #pragma unroll
    for (int r2=0;r2<4;r2++){
      float xr = bf2f(xr_c[r2]), xz = bf2f(xz_c[r2]), xn = bf2f(xn_c[r2]);
      float rg = 1.f/(1.f + __expf(-(xr + acc0[r2] + bh0)));
      float zg = 1.f/(1.f + __expf(-(xz + acc1[r2] + bh1)));
      float nu = xn + rg*(acc2[r2] + bh2);
      float e2 = __expf(2.f*nu);
      float ng = 1.f - 2.f/(e2 + 1.f);          // tanh, inf-safe
      hv[r2] = (1.f - zg)*ng + zg*hv[r2];
    }
    if (t >= t_out0){
      bf16x4 yv;
      yv[0]=f2bf(hv[0]); yv[1]=f2bf(hv[1]); yv[2]=f2bf(hv[2]); yv[3]=f2bf(hv[3]);
      *yst = yv;
    }
    yst += 16384;                     // 32 tiles * 8 * 64 (advance always; deref gated)
    xr_c = xr_n; xz_c = xz_n; xn_c = xn_n; dn_c = dn_n;
  }

  if (kk == NWIN-1){
    #pragma unroll
    for (int r2=0;r2<4;r2++)
      h_last[(size_t)(bt*16+q*4+r2)*H_DIM + w*16 + l] = hv[r2];
  }
}

// ============ K6: act = relu(ys@W_act+b); alpha/beta = softplus(act@W+b)+1 ============
__global__ __launch_bounds__(256) void k_heads(const short* __restrict__ yspk,
                                               const short* __restrict__ Bact,
                                               const float* __restrict__ b_act,
                                               const short* __restrict__ Bhead,
                                               const float* __restrict__ b_alpha,
                                               const float* __restrict__ b_beta,
                                               float* __restrict__ alpha,
                                               float* __restrict__ beta){
  int tid=threadIdx.x, w=tid>>6, lane=tid&63, q=lane>>4, l=lane&15;
  size_t rt = (size_t)blockIdx.x*4 + w;
  __shared__ __align__(16) short tl[4][16][136];
  const bf16x4* ys4 = (const bf16x4*)yspk;
  #pragma unroll
  for (int ct=0; ct<8; ct++){
    bf16x4 v = ys4[(rt*8+ct)*64+lane];
    #pragma unroll
    for (int r2=0;r2<4;r2++) tl[w][q*4+r2][ct*16+l] = v[r2];
  }
  __syncthreads();
  bf16x8 A[4];
  #pragma unroll
  for (int kb=0;kb<4;kb++) A[kb] = *(const bf16x8*)&tl[w][l][kb*32+q*8];
  __syncthreads();
  const bf16x8* BA = (const bf16x8*)Bact;
  f32x4 accA[8];
  #pragma unroll
  for (int ct=0;ct<8;ct++){ f32x4 z = {0.f,0.f,0.f,0.f}; accA[ct]=z; }
  #pragma unroll
  for (int ct=0;ct<8;ct++)
    #pragma unroll
    for (int kb=0;kb<4;kb++)
      accA[ct] = __builtin_amdgcn_mfma_f32_16x16x32_bf16(A[kb], BA[(ct*4+kb)*64+lane], accA[ct], 0,0,0);
  #pragma unroll
  for (int ct=0;ct<8;ct++){
    int col = ct*16 + l;
    float bb = b_act[col];
    #pragma unroll
    for (int r2=0;r2<4;r2++){
      float e = accA[ct][r2] + bb; e = e>0.f ? e : 0.f;
      tl[w][q*4+r2][col] = f2bf(e);
    }
  }
  __syncthreads();
  bf16x8 A2[4];
  #pragma unroll
  for (int kb=0;kb<4;kb++) A2[kb] = *(const bf16x8*)&tl[w][l][kb*32+q*8];
  const bf16x8* BHd = (const bf16x8*)Bhead;
  f32x4 acc = {0.f,0.f,0.f,0.f};
  #pragma unroll
  for (int kb=0;kb<4;kb++)
    acc = __builtin_amdgcn_mfma_f32_16x16x32_bf16(A2[kb], BHd[kb*64+lane], acc, 0,0,0);
  float bb = (l<8) ? b_alpha[l] : b_beta[l-8];
  float* dst = (l<8) ? alpha : beta;
  int cc = (l<8) ? l : l-8;
  #pragma unroll
  for (int r2=0;r2<4;r2++){
    float u = acc[r2] + bb;
    float sp = fmaxf(u,0.f) + log1pf(expf(-fabsf(u)));
    dst[(rt*16 + q*4 + r2)*8 + cc] = sp + 1.f;
  }
}

// ================= host launcher =================
extern "C" void kernel_launch(void* const* d_in, const int* in_sizes, int n_in,
                              void* d_out, int out_size, void* d_ws, size_t ws_size,
                              hipStream_t stream){
  const float* hidden   = (const float*)d_in[0];
  const float* obs      = (const float*)d_in[1];
  const unsigned char* dones = (const unsigned char*)d_in[2];
  const float* mean_obs = (const float*)d_in[3];
  const float* welfS    = (const float*)d_in[4];
  const int*   runcnt   = (const int*)d_in[5];
  const float* W_emb = (const float*)d_in[6];
  const float* b_emb = (const float*)d_in[7];
  const float* Wi    = (const float*)d_in[8];
  const float* Wh    = (const float*)d_in[9];
  const float* bh    = (const float*)d_in[10];
  const float* W_act = (const float*)d_in[11];
  const float* b_act = (const float*)d_in[12];
  const float* W_al  = (const float*)d_in[13];
  const float* b_al  = (const float*)d_in[14];
  const float* W_be  = (const float*)d_in[15];
  const float* b_be  = (const float*)d_in[16];
  float* out = (float*)d_out;
  char*  ws  = (char*)d_ws;

  double* psum = (double*)(ws + OFF_PSUM);
  double* psq  = (double*)(ws + OFF_PSQ);
  float*  wsM  = (float*)(ws + OFF_STATM);
  float*  wsI  = (float*)(ws + OFF_STATI);
  short*  Bemb = (short*)(ws + OFF_WEMB);
  short*  BWi  = (short*)(ws + OFF_WI);
  short*  BWh  = (short*)(ws + OFF_WH);
  short*  Bact = (short*)(ws + OFF_WACT);
  short*  Bhead= (short*)(ws + OFF_WHEAD);
  int*    tlo  = (int*)(ws + OFF_TLO);
  unsigned char* uh = (unsigned char*)(ws + OFF_UH);
  short*  xgpk = (short*)(ws + OFF_XG);
  short*  yspk = (short*)(ws + OFF_YS);

  k_partial<<<1024,256,0,stream>>>(obs, psum, psq);
  k_stats<<<1,1024,0,stream>>>(psum, psq, mean_obs, welfS, runcnt,
                               out+OUT_M, out+OUT_S, wsM, wsI);
  k_sched<<<8,512,0,stream>>>(dones, tlo, uh);
  k_pack_all<<<520,256,0,stream>>>(W_emb, Wi, Wh, W_act, W_al, W_be,
                                   Bemb, BWi, BWh, Bact, Bhead);
  k_embxg<<<8192,512,0,stream>>>(obs, wsM, wsI, Bemb, b_emb, BWi, xgpk);
  k_gru<<<256,512,0,stream>>>(hidden, dones, xgpk, BWh, bh, tlo, uh,
                              yspk, out + OUT_H);
  k_heads<<<2048,256,0,stream>>>(yspk, Bact, b_act, Bhead, b_al, b_be,
                                 out + OUT_ALPHA, out + OUT_BETA);
}